// Round 1
// baseline (836.082 us; speedup 1.0000x reference)
//
#include <hip/hip_runtime.h>
#include <hip/hip_bf16.h>
#include <math.h>

#define NEG_SLOPE 0.2f

// ---------------- CSR build ----------------

__global__ void zero_int(int* __restrict__ p, int n){
    int i = blockIdx.x*256 + threadIdx.x;
    if (i < n) p[i] = 0;
}

__global__ void hist_k(const int* __restrict__ dst, int E, int* __restrict__ cnt){
    int e = blockIdx.x*256 + threadIdx.x;
    if (e < E) atomicAdd(&cnt[dst[e]], 1);
}

// block-level inclusive scan (Hillis-Steele), writes local-exclusive + block total
__global__ void scan1_k(const int* __restrict__ deg, int Nn, int* __restrict__ rp, int* __restrict__ bsum){
    __shared__ int s[256];
    int t = threadIdx.x, b = blockIdx.x;
    int i = b*256 + t;
    int v = (i < Nn) ? deg[i] : 0;
    s[t] = v;
    __syncthreads();
    #pragma unroll
    for (int d = 1; d < 256; d <<= 1){
        int u = (t >= d) ? s[t-d] : 0;
        __syncthreads();
        s[t] += u;
        __syncthreads();
    }
    if (i < Nn) rp[i] = s[t] - v;          // local exclusive
    if (t == 255) bsum[b] = s[255];        // block total
}

__global__ void scan2_k(const int* __restrict__ bsum, int nb, int* __restrict__ bsumx){
    __shared__ int s[256];
    int t = threadIdx.x;
    int v = (t < nb) ? bsum[t] : 0;
    s[t] = v;
    __syncthreads();
    #pragma unroll
    for (int d = 1; d < 256; d <<= 1){
        int u = (t >= d) ? s[t-d] : 0;
        __syncthreads();
        s[t] += u;
        __syncthreads();
    }
    if (t < nb) bsumx[t] = s[t] - v;       // exclusive over block sums
}

__global__ void scan3_k(int* __restrict__ rp, const int* __restrict__ bsumx,
                        int* __restrict__ cnt, int Nn, int E){
    int b = blockIdx.x, t = threadIdx.x;
    int i = b*256 + t;
    if (i < Nn){
        int r = rp[i] + bsumx[b];
        rp[i]  = r;
        cnt[i] = r;                        // cursor init for scatter
    }
    if (b == 0 && t == 0) rp[Nn] = E;
}

__global__ void scatter_k(const int* __restrict__ src, const int* __restrict__ dst,
                          int E, int* __restrict__ cnt, int* __restrict__ esrc){
    int e = blockIdx.x*256 + threadIdx.x;
    if (e < E){
        int d = dst[e];
        int pos = atomicAdd(&cnt[d], 1);
        esrc[pos] = src[e];
    }
}

// ---------------- fused dual fp32 GEMM: C{l,r} = A @ B{l,r} ----------------
// A: [M,K] row-major, B: [K,Nn] row-major, 64x64 tiles, K chunked by 64.
__global__ __launch_bounds__(256) void gemm_dual(
    const float* __restrict__ A,
    const float* __restrict__ Bl, const float* __restrict__ Br,
    float* __restrict__ Cl, float* __restrict__ Cr,
    int M, int Nn, int K)
{
    __shared__ __align__(16) float As[64*64];   // stored transposed: As[k][row]
    __shared__ __align__(16) float Bls[64*64];  // Bls[k][n]
    __shared__ __align__(16) float Brs[64*64];
    int t  = threadIdx.x;
    int tx = t & 15, ty = t >> 4;
    int m0 = blockIdx.x * 64, n0 = blockIdx.y * 64;

    float accl[4][4] = {};
    float accr[4][4] = {};

    for (int kc = 0; kc < K; kc += 64){
        #pragma unroll
        for (int it = 0; it < 4; ++it){
            int row = (t >> 4) + 16*it;       // 0..63
            int kk  = (t & 15) * 4;
            int m = m0 + row;
            float4 v = make_float4(0.f,0.f,0.f,0.f);
            if (m < M) v = *reinterpret_cast<const float4*>(&A[(size_t)m*K + kc + kk]);
            As[(kk+0)*64 + row] = v.x;
            As[(kk+1)*64 + row] = v.y;
            As[(kk+2)*64 + row] = v.z;
            As[(kk+3)*64 + row] = v.w;
        }
        #pragma unroll
        for (int it = 0; it < 4; ++it){
            int kr = (t >> 4) + 16*it;
            int nn = (t & 15) * 4;
            float4 vl = *reinterpret_cast<const float4*>(&Bl[(size_t)(kc+kr)*Nn + n0 + nn]);
            float4 vr = *reinterpret_cast<const float4*>(&Br[(size_t)(kc+kr)*Nn + n0 + nn]);
            *reinterpret_cast<float4*>(&Bls[kr*64 + nn]) = vl;
            *reinterpret_cast<float4*>(&Brs[kr*64 + nn]) = vr;
        }
        __syncthreads();
        #pragma unroll 8
        for (int k = 0; k < 64; ++k){
            float4 a  = *reinterpret_cast<const float4*>(&As [k*64 + ty*4]);
            float4 bl = *reinterpret_cast<const float4*>(&Bls[k*64 + tx*4]);
            float4 br = *reinterpret_cast<const float4*>(&Brs[k*64 + tx*4]);
            float av[4]  = {a.x, a.y, a.z, a.w};
            float blv[4] = {bl.x, bl.y, bl.z, bl.w};
            float brv[4] = {br.x, br.y, br.z, br.w};
            #pragma unroll
            for (int i = 0; i < 4; ++i)
                #pragma unroll
                for (int j = 0; j < 4; ++j){
                    accl[i][j] = fmaf(av[i], blv[j], accl[i][j]);
                    accr[i][j] = fmaf(av[i], brv[j], accr[i][j]);
                }
        }
        __syncthreads();
    }
    #pragma unroll
    for (int i = 0; i < 4; ++i){
        int m = m0 + ty*4 + i;
        if (m < M){
            float4 vl = make_float4(accl[i][0], accl[i][1], accl[i][2], accl[i][3]);
            float4 vr = make_float4(accr[i][0], accr[i][1], accr[i][2], accr[i][3]);
            *reinterpret_cast<float4*>(&Cl[(size_t)m*Nn + n0 + tx*4]) = vl;
            *reinterpret_cast<float4*>(&Cr[(size_t)m*Nn + n0 + tx*4]) = vr;
        }
    }
}

// ---------------- layer-1 aggregation: block=node, wave=head ----------------
__global__ __launch_bounds__(256) void agg1_k(
    const float* __restrict__ xl, const float* __restrict__ xr,
    const int* __restrict__ rp, const int* __restrict__ esrc,
    const float* __restrict__ att, const float* __restrict__ bias,
    float* __restrict__ hout)
{
    int i = blockIdx.x;
    int t = threadIdx.x;              // t = h*64 + c
    float xri = xr[(size_t)i*256 + t];
    float ah  = att[t];               // att1 [4][64] flat
    int beg = rp[i], end = rp[i+1];
    int nE = end - beg;

    float m = -INFINITY, l = 0.f, acc = 0.f;
    float v = xl[(size_t)i*256 + t];  // self-loop first
    for (int j = 0; j <= nE; ++j){
        float vnext = 0.f;
        if (j < nE){
            int sn = esrc[beg + j];
            vnext = xl[(size_t)sn*256 + t];   // prefetch next edge's row
        }
        float e = v + xri;
        e = (e > 0.f) ? e : NEG_SLOPE * e;    // LeakyReLU
        float sc = e * ah;
        #pragma unroll
        for (int off = 32; off > 0; off >>= 1) sc += __shfl_xor(sc, off, 64);
        float mn = fmaxf(m, sc);
        float al = __expf(m - mn);            // 0 on first iter (m=-inf)
        float w  = __expf(sc - mn);
        acc = acc*al + w*v;
        l   = l*al + w;
        m   = mn;
        v = vnext;
    }
    float o = acc / l + bias[t];
    hout[(size_t)i*256 + t] = fmaxf(o, 0.f);  // ReLU
}

// ---------------- layer-2 aggregation + final linear: wave=node ----------------
__global__ __launch_bounds__(256) void agg2_k(
    const float* __restrict__ xl, const float* __restrict__ xr,
    const int* __restrict__ rp, const int* __restrict__ esrc,
    const float* __restrict__ att, const float* __restrict__ bias,
    const float* __restrict__ Wlin, const float* __restrict__ blin,
    float* __restrict__ out, int Nn)
{
    int wave = threadIdx.x >> 6, lane = threadIdx.x & 63;
    int i = blockIdx.x*4 + wave;
    if (i >= Nn) return;
    float xri = xr[(size_t)i*64 + lane];
    float ah  = att[lane];
    int beg = rp[i], end = rp[i+1];
    int nE = end - beg;

    float m = -INFINITY, l = 0.f, acc = 0.f;
    float v = xl[(size_t)i*64 + lane];        // self-loop first
    for (int j = 0; j <= nE; ++j){
        float vnext = 0.f;
        if (j < nE){
            int sn = esrc[beg + j];
            vnext = xl[(size_t)sn*64 + lane];
        }
        float e = v + xri;
        e = (e > 0.f) ? e : NEG_SLOPE * e;
        float sc = e * ah;
        #pragma unroll
        for (int off = 32; off > 0; off >>= 1) sc += __shfl_xor(sc, off, 64);
        float mn = fmaxf(m, sc);
        float al = __expf(m - mn);
        float w  = __expf(sc - mn);
        acc = acc*al + w*v;
        l   = l*al + w;
        m   = mn;
        v = vnext;
    }
    float hc = fmaxf(acc / l + bias[lane], 0.f);   // ReLU(h2)
    // out[i][j] = sum_c hc[c] * Wlin[c][j] + blin[j]
    #pragma unroll
    for (int j = 0; j < 10; ++j){
        float p = hc * Wlin[lane*10 + j];
        #pragma unroll
        for (int off = 32; off > 0; off >>= 1) p += __shfl_xor(p, off, 64);
        if (lane == 0) out[(size_t)i*10 + j] = p + blin[j];
    }
}

// ---------------- launch ----------------

extern "C" void kernel_launch(void* const* d_in, const int* in_sizes, int n_in,
                              void* d_out, int out_size, void* d_ws, size_t ws_size,
                              hipStream_t stream)
{
    const float* x    = (const float*)d_in[0];
    const int*   ei   = (const int*)  d_in[1];
    const float* Wl1  = (const float*)d_in[2];
    const float* Wr1  = (const float*)d_in[3];
    const float* att1 = (const float*)d_in[4];
    const float* b1   = (const float*)d_in[5];
    const float* Wl2  = (const float*)d_in[6];
    const float* Wr2  = (const float*)d_in[7];
    const float* att2 = (const float*)d_in[8];
    const float* b2   = (const float*)d_in[9];
    const float* Wlin = (const float*)d_in[10];
    const float* blin = (const float*)d_in[11];
    float* out = (float*)d_out;

    const int N = in_sizes[0] / 256;
    const int E = in_sizes[1] / 2;
    const int* srcp = ei;
    const int* dstp = ei + E;

    char* ws = (char*)d_ws;
    size_t off = 0;
    auto alloc = [&](size_t bytes)->char*{
        char* p = ws + off;
        off += (bytes + 255) & ~(size_t)255;
        return p;
    };
    float* xl1 = (float*)alloc((size_t)N*256*4);
    float* xr1 = (float*)alloc((size_t)N*256*4);
    float* h1  = (float*)alloc((size_t)N*256*4);
    float* xl2 = (float*)alloc((size_t)N*64*4);
    float* xr2 = (float*)alloc((size_t)N*64*4);
    int* rp    = (int*)alloc((size_t)(N+1)*4);
    int* cnt   = (int*)alloc((size_t)N*4);
    int* bsum  = (int*)alloc(256*4);
    int* bsumx = (int*)alloc(256*4);
    int* esrc  = (int*)alloc((size_t)E*4);
    (void)ws_size;

    const int nb = (N + 255) / 256;     // 196 for N=50000; must be <= 256
    const int eb = (E + 255) / 256;

    hipLaunchKernelGGL(zero_int,  dim3(nb), dim3(256), 0, stream, cnt, N);
    hipLaunchKernelGGL(hist_k,    dim3(eb), dim3(256), 0, stream, dstp, E, cnt);
    hipLaunchKernelGGL(scan1_k,   dim3(nb), dim3(256), 0, stream, cnt, N, rp, bsum);
    hipLaunchKernelGGL(scan2_k,   dim3(1),  dim3(256), 0, stream, bsum, nb, bsumx);
    hipLaunchKernelGGL(scan3_k,   dim3(nb), dim3(256), 0, stream, rp, bsumx, cnt, N, E);
    hipLaunchKernelGGL(scatter_k, dim3(eb), dim3(256), 0, stream, srcp, dstp, E, cnt, esrc);

    // layer 1: xl1 = x@Wl1, xr1 = x@Wr1
    hipLaunchKernelGGL(gemm_dual, dim3((N+63)/64, 4), dim3(256), 0, stream,
                       x, Wl1, Wr1, xl1, xr1, N, 256, 256);
    hipLaunchKernelGGL(agg1_k, dim3(N), dim3(256), 0, stream,
                       xl1, xr1, rp, esrc, att1, b1, h1);
    // layer 2: xl2 = h1@Wl2, xr2 = h1@Wr2
    hipLaunchKernelGGL(gemm_dual, dim3((N+63)/64, 1), dim3(256), 0, stream,
                       h1, Wl2, Wr2, xl2, xr2, N, 64, 256);
    hipLaunchKernelGGL(agg2_k, dim3((N+3)/4), dim3(256), 0, stream,
                       xl2, xr2, rp, esrc, att2, b2, Wlin, blin, out, N);
}

// Round 2
// 641.111 us; speedup vs baseline: 1.3041x; 1.3041x over previous
//
#include <hip/hip_runtime.h>
#include <hip/hip_bf16.h>
#include <math.h>

#define NEG_SLOPE 0.2f

// ---------------- CSR build ----------------

__global__ void zero_int(int* __restrict__ p, int n){
    int i = blockIdx.x*256 + threadIdx.x;
    if (i < n) p[i] = 0;
}

__global__ void hist_k(const int* __restrict__ dst, int E, int* __restrict__ cnt){
    int e = blockIdx.x*256 + threadIdx.x;
    if (e < E) atomicAdd(&cnt[dst[e]], 1);
}

__global__ void scan1_k(const int* __restrict__ deg, int Nn, int* __restrict__ rp, int* __restrict__ bsum){
    __shared__ int s[256];
    int t = threadIdx.x, b = blockIdx.x;
    int i = b*256 + t;
    int v = (i < Nn) ? deg[i] : 0;
    s[t] = v;
    __syncthreads();
    #pragma unroll
    for (int d = 1; d < 256; d <<= 1){
        int u = (t >= d) ? s[t-d] : 0;
        __syncthreads();
        s[t] += u;
        __syncthreads();
    }
    if (i < Nn) rp[i] = s[t] - v;
    if (t == 255) bsum[b] = s[255];
}

__global__ void scan2_k(const int* __restrict__ bsum, int nb, int* __restrict__ bsumx){
    __shared__ int s[256];
    int t = threadIdx.x;
    int v = (t < nb) ? bsum[t] : 0;
    s[t] = v;
    __syncthreads();
    #pragma unroll
    for (int d = 1; d < 256; d <<= 1){
        int u = (t >= d) ? s[t-d] : 0;
        __syncthreads();
        s[t] += u;
        __syncthreads();
    }
    if (t < nb) bsumx[t] = s[t] - v;
}

__global__ void scan3_k(int* __restrict__ rp, const int* __restrict__ bsumx,
                        int* __restrict__ cnt, int Nn, int E){
    int b = blockIdx.x, t = threadIdx.x;
    int i = b*256 + t;
    if (i < Nn){
        int r = rp[i] + bsumx[b];
        rp[i]  = r;
        cnt[i] = r;
    }
    if (b == 0 && t == 0) rp[Nn] = E;
}

__global__ void scatter_k(const int* __restrict__ src, const int* __restrict__ dst,
                          int E, int* __restrict__ cnt, int* __restrict__ esrc){
    int e = blockIdx.x*256 + threadIdx.x;
    if (e < E){
        int d = dst[e];
        int pos = atomicAdd(&cnt[d], 1);
        esrc[pos] = src[e];
    }
}

// ---------------- fused dual fp32 GEMM: C{l,r} = A @ B{l,r} ----------------
__global__ __launch_bounds__(256) void gemm_dual(
    const float* __restrict__ A,
    const float* __restrict__ Bl, const float* __restrict__ Br,
    float* __restrict__ Cl, float* __restrict__ Cr,
    int M, int Nn, int K)
{
    __shared__ __align__(16) float As[64*64];   // transposed: As[k][row]
    __shared__ __align__(16) float Bls[64*64];  // Bls[k][n]
    __shared__ __align__(16) float Brs[64*64];
    int t  = threadIdx.x;
    int tx = t & 15, ty = t >> 4;
    int m0 = blockIdx.x * 64, n0 = blockIdx.y * 64;

    float accl[4][4] = {};
    float accr[4][4] = {};

    for (int kc = 0; kc < K; kc += 64){
        #pragma unroll
        for (int it = 0; it < 4; ++it){
            int row = (t >> 4) + 16*it;
            int kk  = (t & 15) * 4;
            int m = m0 + row;
            float4 v = make_float4(0.f,0.f,0.f,0.f);
            if (m < M) v = *reinterpret_cast<const float4*>(&A[(size_t)m*K + kc + kk]);
            As[(kk+0)*64 + row] = v.x;
            As[(kk+1)*64 + row] = v.y;
            As[(kk+2)*64 + row] = v.z;
            As[(kk+3)*64 + row] = v.w;
        }
        #pragma unroll
        for (int it = 0; it < 4; ++it){
            int kr = (t >> 4) + 16*it;
            int nn = (t & 15) * 4;
            float4 vl = *reinterpret_cast<const float4*>(&Bl[(size_t)(kc+kr)*Nn + n0 + nn]);
            float4 vr = *reinterpret_cast<const float4*>(&Br[(size_t)(kc+kr)*Nn + n0 + nn]);
            *reinterpret_cast<float4*>(&Bls[kr*64 + nn]) = vl;
            *reinterpret_cast<float4*>(&Brs[kr*64 + nn]) = vr;
        }
        __syncthreads();
        #pragma unroll 8
        for (int k = 0; k < 64; ++k){
            float4 a  = *reinterpret_cast<const float4*>(&As [k*64 + ty*4]);
            float4 bl = *reinterpret_cast<const float4*>(&Bls[k*64 + tx*4]);
            float4 br = *reinterpret_cast<const float4*>(&Brs[k*64 + tx*4]);
            float av[4]  = {a.x, a.y, a.z, a.w};
            float blv[4] = {bl.x, bl.y, bl.z, bl.w};
            float brv[4] = {br.x, br.y, br.z, br.w};
            #pragma unroll
            for (int i = 0; i < 4; ++i)
                #pragma unroll
                for (int j = 0; j < 4; ++j){
                    accl[i][j] = fmaf(av[i], blv[j], accl[i][j]);
                    accr[i][j] = fmaf(av[i], brv[j], accr[i][j]);
                }
        }
        __syncthreads();
    }
    #pragma unroll
    for (int i = 0; i < 4; ++i){
        int m = m0 + ty*4 + i;
        if (m < M){
            float4 vl = make_float4(accl[i][0], accl[i][1], accl[i][2], accl[i][3]);
            float4 vr = make_float4(accr[i][0], accr[i][1], accr[i][2], accr[i][3]);
            *reinterpret_cast<float4*>(&Cl[(size_t)m*Nn + n0 + tx*4]) = vl;
            *reinterpret_cast<float4*>(&Cr[(size_t)m*Nn + n0 + tx*4]) = vr;
        }
    }
}

__device__ __forceinline__ float lrelu(float x){ return fmaxf(x, NEG_SLOPE * x); }

// ---------------- layer-1 aggregation: wave per node, lane = 4 channels ----------------
// lane l: head h = l>>4, channels 4*l .. 4*l+3. 16-lane group == one head.
__global__ __launch_bounds__(256) void agg1_k(
    const float* __restrict__ xl, const float* __restrict__ xr,
    const int* __restrict__ rp, const int* __restrict__ esrc,
    const float* __restrict__ att, const float* __restrict__ bias,
    float* __restrict__ hout, int Nn)
{
    int wave = threadIdx.x >> 6, lane = threadIdx.x & 63;
    int i = blockIdx.x*4 + wave;
    if (i >= Nn) return;
    int off = lane*4;
    float4 xr4 = *reinterpret_cast<const float4*>(&xr[(size_t)i*256 + off]);
    float4 at4 = *reinterpret_cast<const float4*>(&att[off]);
    int beg = rp[i], nE = rp[i+1] - beg;

    float m = -1e30f, l = 0.f;
    float4 acc = make_float4(0.f,0.f,0.f,0.f);
    float4 v = *reinterpret_cast<const float4*>(&xl[(size_t)i*256 + off]);  // self-loop
    for (int j = 0; j <= nE; ++j){
        float4 vn = make_float4(0.f,0.f,0.f,0.f);
        if (j < nE){
            int sn = esrc[beg + j];
            vn = *reinterpret_cast<const float4*>(&xl[(size_t)sn*256 + off]);  // prefetch
        }
        float sc = lrelu(v.x + xr4.x) * at4.x
                 + lrelu(v.y + xr4.y) * at4.y
                 + lrelu(v.z + xr4.z) * at4.z
                 + lrelu(v.w + xr4.w) * at4.w;
        sc += __shfl_xor(sc, 8, 64);
        sc += __shfl_xor(sc, 4, 64);
        sc += __shfl_xor(sc, 2, 64);
        sc += __shfl_xor(sc, 1, 64);
        float mn = fmaxf(m, sc);
        float al = __expf(m - mn);
        float w  = __expf(sc - mn);
        acc.x = acc.x*al + w*v.x;
        acc.y = acc.y*al + w*v.y;
        acc.z = acc.z*al + w*v.z;
        acc.w = acc.w*al + w*v.w;
        l = l*al + w;
        m = mn;
        v = vn;
    }
    float inv = 1.f / l;
    float4 b4 = *reinterpret_cast<const float4*>(&bias[off]);
    float4 o;
    o.x = fmaxf(acc.x*inv + b4.x, 0.f);
    o.y = fmaxf(acc.y*inv + b4.y, 0.f);
    o.z = fmaxf(acc.z*inv + b4.z, 0.f);
    o.w = fmaxf(acc.w*inv + b4.w, 0.f);
    *reinterpret_cast<float4*>(&hout[(size_t)i*256 + off]) = o;
}

// ---------------- layer-2 aggregation + final linear: wave per node, 4 quarters ----------------
// quarter q (lanes 16q..16q+15) handles items q, q+4, ... of the (self + edges) list.
__global__ __launch_bounds__(256) void agg2_k(
    const float* __restrict__ xl, const float* __restrict__ xr,
    const int* __restrict__ rp, const int* __restrict__ esrc,
    const float* __restrict__ att, const float* __restrict__ bias,
    const float* __restrict__ Wlin, const float* __restrict__ blin,
    float* __restrict__ out, int Nn)
{
    int wave = threadIdx.x >> 6, lane = threadIdx.x & 63;
    int i = blockIdx.x*4 + wave;
    if (i >= Nn) return;
    int q = lane >> 4, r = lane & 15;
    int off = r*4;
    float4 xr4 = *reinterpret_cast<const float4*>(&xr[(size_t)i*64 + off]);
    float4 at4 = *reinterpret_cast<const float4*>(&att[off]);
    int beg = rp[i], nE = rp[i+1] - beg;
    int nItems = nE + 1;

    float m = -1e30f, l = 0.f;
    float4 acc = make_float4(0.f,0.f,0.f,0.f);
    for (int j = q; j < nItems; j += 4){
        float4 v;
        if (j == 0){
            v = *reinterpret_cast<const float4*>(&xl[(size_t)i*64 + off]);
        } else {
            int sn = esrc[beg + j - 1];
            v = *reinterpret_cast<const float4*>(&xl[(size_t)sn*64 + off]);
        }
        float sc = lrelu(v.x + xr4.x) * at4.x
                 + lrelu(v.y + xr4.y) * at4.y
                 + lrelu(v.z + xr4.z) * at4.z
                 + lrelu(v.w + xr4.w) * at4.w;
        sc += __shfl_xor(sc, 8, 64);
        sc += __shfl_xor(sc, 4, 64);
        sc += __shfl_xor(sc, 2, 64);
        sc += __shfl_xor(sc, 1, 64);
        float mn = fmaxf(m, sc);
        float al = __expf(m - mn);
        float w  = __expf(sc - mn);
        acc.x = acc.x*al + w*v.x;
        acc.y = acc.y*al + w*v.y;
        acc.z = acc.z*al + w*v.z;
        acc.w = acc.w*al + w*v.w;
        l = l*al + w;
        m = mn;
    }
    // merge the 4 quarters' online-softmax partials
    #pragma unroll
    for (int s = 16; s <= 32; s <<= 1){
        float m2 = __shfl_xor(m, s, 64);
        float l2 = __shfl_xor(l, s, 64);
        float ax = __shfl_xor(acc.x, s, 64);
        float ay = __shfl_xor(acc.y, s, 64);
        float az = __shfl_xor(acc.z, s, 64);
        float aw = __shfl_xor(acc.w, s, 64);
        float mn = fmaxf(m, m2);
        float a1 = __expf(m - mn);
        float a2 = __expf(m2 - mn);
        acc.x = acc.x*a1 + ax*a2;
        acc.y = acc.y*a1 + ay*a2;
        acc.z = acc.z*a1 + az*a2;
        acc.w = acc.w*a1 + aw*a2;
        l = l*a1 + l2*a2;
        m = mn;
    }
    float inv = 1.f / l;
    float4 b4 = *reinterpret_cast<const float4*>(&bias[off]);
    float4 hc;
    hc.x = fmaxf(acc.x*inv + b4.x, 0.f);
    hc.y = fmaxf(acc.y*inv + b4.y, 0.f);
    hc.z = fmaxf(acc.z*inv + b4.z, 0.f);
    hc.w = fmaxf(acc.w*inv + b4.w, 0.f);
    // final linear: quarter q computes classes q, q+4, q+8 (<10)
    for (int c = q; c < 10; c += 4){
        float p = hc.x * Wlin[(off+0)*10 + c]
                + hc.y * Wlin[(off+1)*10 + c]
                + hc.z * Wlin[(off+2)*10 + c]
                + hc.w * Wlin[(off+3)*10 + c];
        p += __shfl_xor(p, 8, 64);
        p += __shfl_xor(p, 4, 64);
        p += __shfl_xor(p, 2, 64);
        p += __shfl_xor(p, 1, 64);
        if (r == 0) out[(size_t)i*10 + c] = p + blin[c];
    }
}

// ---------------- launch ----------------

extern "C" void kernel_launch(void* const* d_in, const int* in_sizes, int n_in,
                              void* d_out, int out_size, void* d_ws, size_t ws_size,
                              hipStream_t stream)
{
    const float* x    = (const float*)d_in[0];
    const int*   ei   = (const int*)  d_in[1];
    const float* Wl1  = (const float*)d_in[2];
    const float* Wr1  = (const float*)d_in[3];
    const float* att1 = (const float*)d_in[4];
    const float* b1   = (const float*)d_in[5];
    const float* Wl2  = (const float*)d_in[6];
    const float* Wr2  = (const float*)d_in[7];
    const float* att2 = (const float*)d_in[8];
    const float* b2   = (const float*)d_in[9];
    const float* Wlin = (const float*)d_in[10];
    const float* blin = (const float*)d_in[11];
    float* out = (float*)d_out;

    const int N = in_sizes[0] / 256;
    const int E = in_sizes[1] / 2;
    const int* srcp = ei;
    const int* dstp = ei + E;

    char* ws = (char*)d_ws;
    size_t off = 0;
    auto alloc = [&](size_t bytes)->char*{
        char* p = ws + off;
        off += (bytes + 255) & ~(size_t)255;
        return p;
    };
    float* xl1 = (float*)alloc((size_t)N*256*4);
    float* xr1 = (float*)alloc((size_t)N*256*4);
    float* h1  = (float*)alloc((size_t)N*256*4);
    float* xl2 = (float*)alloc((size_t)N*64*4);
    float* xr2 = (float*)alloc((size_t)N*64*4);
    int* rp    = (int*)alloc((size_t)(N+1)*4);
    int* cnt   = (int*)alloc((size_t)N*4);
    int* bsum  = (int*)alloc(256*4);
    int* bsumx = (int*)alloc(256*4);
    int* esrc  = (int*)alloc((size_t)E*4);
    (void)ws_size;

    const int nb = (N + 255) / 256;
    const int eb = (E + 255) / 256;

    hipLaunchKernelGGL(zero_int,  dim3(nb), dim3(256), 0, stream, cnt, N);
    hipLaunchKernelGGL(hist_k,    dim3(eb), dim3(256), 0, stream, dstp, E, cnt);
    hipLaunchKernelGGL(scan1_k,   dim3(nb), dim3(256), 0, stream, cnt, N, rp, bsum);
    hipLaunchKernelGGL(scan2_k,   dim3(1),  dim3(256), 0, stream, bsum, nb, bsumx);
    hipLaunchKernelGGL(scan3_k,   dim3(nb), dim3(256), 0, stream, rp, bsumx, cnt, N, E);
    hipLaunchKernelGGL(scatter_k, dim3(eb), dim3(256), 0, stream, srcp, dstp, E, cnt, esrc);

    hipLaunchKernelGGL(gemm_dual, dim3((N+63)/64, 4), dim3(256), 0, stream,
                       x, Wl1, Wr1, xl1, xr1, N, 256, 256);
    hipLaunchKernelGGL(agg1_k, dim3((N+3)/4), dim3(256), 0, stream,
                       xl1, xr1, rp, esrc, att1, b1, h1, N);
    hipLaunchKernelGGL(gemm_dual, dim3((N+63)/64, 1), dim3(256), 0, stream,
                       h1, Wl2, Wr2, xl2, xr2, N, 64, 256);
    hipLaunchKernelGGL(agg2_k, dim3((N+3)/4), dim3(256), 0, stream,
                       xl2, xr2, rp, esrc, att2, b2, Wlin, blin, out, N);
}

// Round 3
// 508.378 us; speedup vs baseline: 1.6446x; 1.2611x over previous
//
#include <hip/hip_runtime.h>
#include <hip/hip_bf16.h>
#include <math.h>

#define NEG_SLOPE 0.2f

typedef short bf16x8 __attribute__((ext_vector_type(8)));
typedef float f32x4  __attribute__((ext_vector_type(4)));

__device__ __forceinline__ unsigned short f2bf(float f){
    unsigned int u = __float_as_uint(f);
    u += 0x7fffu + ((u >> 16) & 1u);          // RNE
    return (unsigned short)(u >> 16);
}
__device__ __forceinline__ float bf2f(unsigned short h){
    return __uint_as_float(((unsigned int)h) << 16);
}
__device__ __forceinline__ void split_bf(float v, unsigned short& h, unsigned short& l){
    h = f2bf(v);
    l = f2bf(v - bf2f(h));
}

// ---------------- CSR build ----------------

__global__ void zero_int(int* __restrict__ p, int n){
    int i = blockIdx.x*256 + threadIdx.x;
    if (i < n) p[i] = 0;
}

__global__ void hist_k(const int* __restrict__ dst, int E, int* __restrict__ cnt){
    int e = blockIdx.x*256 + threadIdx.x;
    if (e < E) atomicAdd(&cnt[dst[e]], 1);
}

__global__ void scan1_k(const int* __restrict__ deg, int Nn, int* __restrict__ rp, int* __restrict__ bsum){
    __shared__ int s[256];
    int t = threadIdx.x, b = blockIdx.x;
    int i = b*256 + t;
    int v = (i < Nn) ? deg[i] : 0;
    s[t] = v;
    __syncthreads();
    #pragma unroll
    for (int d = 1; d < 256; d <<= 1){
        int u = (t >= d) ? s[t-d] : 0;
        __syncthreads();
        s[t] += u;
        __syncthreads();
    }
    if (i < Nn) rp[i] = s[t] - v;
    if (t == 255) bsum[b] = s[255];
}

__global__ void scan2_k(const int* __restrict__ bsum, int nb, int* __restrict__ bsumx){
    __shared__ int s[256];
    int t = threadIdx.x;
    int v = (t < nb) ? bsum[t] : 0;
    s[t] = v;
    __syncthreads();
    #pragma unroll
    for (int d = 1; d < 256; d <<= 1){
        int u = (t >= d) ? s[t-d] : 0;
        __syncthreads();
        s[t] += u;
        __syncthreads();
    }
    if (t < nb) bsumx[t] = s[t] - v;
}

__global__ void scan3_k(int* __restrict__ rp, const int* __restrict__ bsumx,
                        int* __restrict__ cnt, int Nn, int E){
    int b = blockIdx.x, t = threadIdx.x;
    int i = b*256 + t;
    if (i < Nn){
        int r = rp[i] + bsumx[b];
        rp[i]  = r;
        cnt[i] = r;
    }
    if (b == 0 && t == 0) rp[Nn] = E;
}

__global__ void scatter_k(const int* __restrict__ src, const int* __restrict__ dst,
                          int E, int* __restrict__ cnt, int* __restrict__ esrc){
    int e = blockIdx.x*256 + threadIdx.x;
    if (e < E){
        int d = dst[e];
        int pos = atomicAdd(&cnt[d], 1);
        esrc[pos] = src[e];
    }
}

// ---------------- conversions ----------------

// fp32 -> bf16 hi/lo split, vectorized x4
__global__ void cvt_split_k(const float* __restrict__ X,
                            unsigned short* __restrict__ H, unsigned short* __restrict__ L, int n4){
    int i = blockIdx.x*256 + threadIdx.x;
    if (i >= n4) return;
    float4 v = reinterpret_cast<const float4*>(X)[i];
    unsigned short h0,h1,h2,h3,l0,l1,l2,l3;
    split_bf(v.x, h0, l0); split_bf(v.y, h1, l1);
    split_bf(v.z, h2, l2); split_bf(v.w, h3, l3);
    uint2 ph, pl;
    ph.x = (unsigned)h0 | ((unsigned)h1 << 16);
    ph.y = (unsigned)h2 | ((unsigned)h3 << 16);
    pl.x = (unsigned)l0 | ((unsigned)l1 << 16);
    pl.y = (unsigned)l2 | ((unsigned)l3 << 16);
    reinterpret_cast<uint2*>(H)[i] = ph;
    reinterpret_cast<uint2*>(L)[i] = pl;
}

// weights [K][Nw] (two of them) -> transposed split Bt[2*Nw][K] bf16 hi/lo
__global__ void cvt_w_k(const float* __restrict__ Wl, const float* __restrict__ Wr,
                        int Nw, int K,
                        unsigned short* __restrict__ Bth, unsigned short* __restrict__ Btl){
    int t = blockIdx.x*256 + threadIdx.x;
    int total = 2*Nw*K;
    if (t >= total) return;
    int k = t & (K-1);
    int n = t >> 8;                 // K == 256
    float v = (n < Nw) ? Wl[(size_t)k*Nw + n] : Wr[(size_t)k*Nw + (n - Nw)];
    unsigned short h, l;
    split_bf(v, h, l);
    Bth[t] = h; Btl[t] = l;
}

// ---------------- split-bf16 MFMA GEMM: C = A @ B,  B given as [Ntot][K] ----------------
// C fp32 [M][Ntot]. Tile 128x128, 4 waves (2x2), 16x16x32 bf16 MFMA,
// 3 MFMAs per tile-step: Ah*Bh + Ah*Bl + Al*Bh.
__global__ __launch_bounds__(256) void gemm_mfma(
    const unsigned short* __restrict__ Ah, const unsigned short* __restrict__ Al,
    const unsigned short* __restrict__ Bh, const unsigned short* __restrict__ Bl,
    float* __restrict__ C, int M, int Ntot, int K)
{
    // padded rows: 32 used + 8 pad = 40 bf16 (80 B stride -> conflict-free b128)
    __shared__ __align__(16) unsigned short sAh[128*40];
    __shared__ __align__(16) unsigned short sAl[128*40];
    __shared__ __align__(16) unsigned short sBh[128*40];
    __shared__ __align__(16) unsigned short sBl[128*40];

    int t = threadIdx.x;
    int lane = t & 63, wave = t >> 6;
    int wm = (wave >> 1) * 64, wn = (wave & 1) * 64;
    int m0 = blockIdx.y * 128, n0 = blockIdx.x * 128;
    int lm = lane & 15, kq = lane >> 4;

    f32x4 acc[4][4] = {};   // [m-tile][n-tile]

    for (int kc = 0; kc < K; kc += 32){
        __syncthreads();
        #pragma unroll
        for (int it = 0; it < 2; ++it){
            int idx = t + 256*it;
            int r = idx >> 2, s = (idx & 3) * 8;
            size_t ga = (size_t)(m0 + r) * K + kc + s;
            uint4 vh = make_uint4(0u,0u,0u,0u), vl = vh;
            if (m0 + r < M){
                vh = *reinterpret_cast<const uint4*>(Ah + ga);
                vl = *reinterpret_cast<const uint4*>(Al + ga);
            }
            *reinterpret_cast<uint4*>(sAh + r*40 + s) = vh;
            *reinterpret_cast<uint4*>(sAl + r*40 + s) = vl;
            size_t gb = (size_t)(n0 + r) * K + kc + s;
            *reinterpret_cast<uint4*>(sBh + r*40 + s) = *reinterpret_cast<const uint4*>(Bh + gb);
            *reinterpret_cast<uint4*>(sBl + r*40 + s) = *reinterpret_cast<const uint4*>(Bl + gb);
        }
        __syncthreads();

        bf16x8 fah[4], fal[4], fbh[4], fbl[4];
        #pragma unroll
        for (int i = 0; i < 4; ++i){
            int ar = wm + i*16 + lm;
            fah[i] = *reinterpret_cast<const bf16x8*>(sAh + ar*40 + kq*8);
            fal[i] = *reinterpret_cast<const bf16x8*>(sAl + ar*40 + kq*8);
            int br = wn + i*16 + lm;
            fbh[i] = *reinterpret_cast<const bf16x8*>(sBh + br*40 + kq*8);
            fbl[i] = *reinterpret_cast<const bf16x8*>(sBl + br*40 + kq*8);
        }
        #pragma unroll
        for (int i = 0; i < 4; ++i)
            #pragma unroll
            for (int j = 0; j < 4; ++j){
                acc[i][j] = __builtin_amdgcn_mfma_f32_16x16x32_bf16(fah[i], fbh[j], acc[i][j], 0, 0, 0);
                acc[i][j] = __builtin_amdgcn_mfma_f32_16x16x32_bf16(fah[i], fbl[j], acc[i][j], 0, 0, 0);
                acc[i][j] = __builtin_amdgcn_mfma_f32_16x16x32_bf16(fal[i], fbh[j], acc[i][j], 0, 0, 0);
            }
    }

    #pragma unroll
    for (int i = 0; i < 4; ++i){
        #pragma unroll
        for (int r = 0; r < 4; ++r){
            int m = m0 + wm + i*16 + kq*4 + r;
            if (m < M){
                #pragma unroll
                for (int j = 0; j < 4; ++j){
                    C[(size_t)m*Ntot + n0 + wn + j*16 + lm] = acc[i][j][r];
                }
            }
        }
    }
}

__device__ __forceinline__ float lrelu(float x){ return fmaxf(x, NEG_SLOPE * x); }

// ---------------- layer-1 aggregation: wave per node, lane = 4 channels ----------------
// xlr [N][512]: cols 0..255 = xl, 256..511 = xr. Writes h1 as bf16 hi/lo splits.
__global__ __launch_bounds__(256) void agg1_k(
    const float* __restrict__ xlr,
    const int* __restrict__ rp, const int* __restrict__ esrc,
    const float* __restrict__ att, const float* __restrict__ bias,
    unsigned short* __restrict__ h1h, unsigned short* __restrict__ h1l, int Nn)
{
    int wave = threadIdx.x >> 6, lane = threadIdx.x & 63;
    int i = blockIdx.x*4 + wave;
    if (i >= Nn) return;
    int off = lane*4;
    float4 xr4 = *reinterpret_cast<const float4*>(&xlr[(size_t)i*512 + 256 + off]);
    float4 at4 = *reinterpret_cast<const float4*>(&att[off]);
    int beg = rp[i], nE = rp[i+1] - beg;

    float m = -1e30f, l = 0.f;
    float4 acc = make_float4(0.f,0.f,0.f,0.f);
    float4 v = *reinterpret_cast<const float4*>(&xlr[(size_t)i*512 + off]);  // self-loop
    for (int j = 0; j <= nE; ++j){
        float4 vn = make_float4(0.f,0.f,0.f,0.f);
        if (j < nE){
            int sn = esrc[beg + j];
            vn = *reinterpret_cast<const float4*>(&xlr[(size_t)sn*512 + off]);  // prefetch
        }
        float sc = lrelu(v.x + xr4.x) * at4.x
                 + lrelu(v.y + xr4.y) * at4.y
                 + lrelu(v.z + xr4.z) * at4.z
                 + lrelu(v.w + xr4.w) * at4.w;
        sc += __shfl_xor(sc, 8, 64);
        sc += __shfl_xor(sc, 4, 64);
        sc += __shfl_xor(sc, 2, 64);
        sc += __shfl_xor(sc, 1, 64);
        float mn = fmaxf(m, sc);
        float al = __expf(m - mn);
        float w  = __expf(sc - mn);
        acc.x = acc.x*al + w*v.x;
        acc.y = acc.y*al + w*v.y;
        acc.z = acc.z*al + w*v.z;
        acc.w = acc.w*al + w*v.w;
        l = l*al + w;
        m = mn;
        v = vn;
    }
    float inv = 1.f / l;
    float4 b4 = *reinterpret_cast<const float4*>(&bias[off]);
    float o0 = fmaxf(acc.x*inv + b4.x, 0.f);
    float o1 = fmaxf(acc.y*inv + b4.y, 0.f);
    float o2 = fmaxf(acc.z*inv + b4.z, 0.f);
    float o3 = fmaxf(acc.w*inv + b4.w, 0.f);
    unsigned short h0,h1,h2,h3,l0,l1,l2,l3;
    split_bf(o0,h0,l0); split_bf(o1,h1,l1); split_bf(o2,h2,l2); split_bf(o3,h3,l3);
    uint2 ph, pl;
    ph.x = (unsigned)h0 | ((unsigned)h1 << 16);
    ph.y = (unsigned)h2 | ((unsigned)h3 << 16);
    pl.x = (unsigned)l0 | ((unsigned)l1 << 16);
    pl.y = (unsigned)l2 | ((unsigned)l3 << 16);
    *reinterpret_cast<uint2*>(&h1h[(size_t)i*256 + off]) = ph;
    *reinterpret_cast<uint2*>(&h1l[(size_t)i*256 + off]) = pl;
}

// ---------------- layer-2 aggregation + final linear: wave per node, 4 quarters ----------------
// xlr2 [N][128]: cols 0..63 = xl, 64..127 = xr.
__global__ __launch_bounds__(256) void agg2_k(
    const float* __restrict__ xlr,
    const int* __restrict__ rp, const int* __restrict__ esrc,
    const float* __restrict__ att, const float* __restrict__ bias,
    const float* __restrict__ Wlin, const float* __restrict__ blin,
    float* __restrict__ out, int Nn)
{
    int wave = threadIdx.x >> 6, lane = threadIdx.x & 63;
    int i = blockIdx.x*4 + wave;
    if (i >= Nn) return;
    int q = lane >> 4, r = lane & 15;
    int off = r*4;
    float4 xr4 = *reinterpret_cast<const float4*>(&xlr[(size_t)i*128 + 64 + off]);
    float4 at4 = *reinterpret_cast<const float4*>(&att[off]);
    int beg = rp[i], nE = rp[i+1] - beg;
    int nItems = nE + 1;

    float m = -1e30f, l = 0.f;
    float4 acc = make_float4(0.f,0.f,0.f,0.f);
    for (int j = q; j < nItems; j += 4){
        float4 v;
        if (j == 0){
            v = *reinterpret_cast<const float4*>(&xlr[(size_t)i*128 + off]);
        } else {
            int sn = esrc[beg + j - 1];
            v = *reinterpret_cast<const float4*>(&xlr[(size_t)sn*128 + off]);
        }
        float sc = lrelu(v.x + xr4.x) * at4.x
                 + lrelu(v.y + xr4.y) * at4.y
                 + lrelu(v.z + xr4.z) * at4.z
                 + lrelu(v.w + xr4.w) * at4.w;
        sc += __shfl_xor(sc, 8, 64);
        sc += __shfl_xor(sc, 4, 64);
        sc += __shfl_xor(sc, 2, 64);
        sc += __shfl_xor(sc, 1, 64);
        float mn = fmaxf(m, sc);
        float al = __expf(m - mn);
        float w  = __expf(sc - mn);
        acc.x = acc.x*al + w*v.x;
        acc.y = acc.y*al + w*v.y;
        acc.z = acc.z*al + w*v.z;
        acc.w = acc.w*al + w*v.w;
        l = l*al + w;
        m = mn;
    }
    #pragma unroll
    for (int s = 16; s <= 32; s <<= 1){
        float m2 = __shfl_xor(m, s, 64);
        float l2 = __shfl_xor(l, s, 64);
        float ax = __shfl_xor(acc.x, s, 64);
        float ay = __shfl_xor(acc.y, s, 64);
        float az = __shfl_xor(acc.z, s, 64);
        float aw = __shfl_xor(acc.w, s, 64);
        float mn = fmaxf(m, m2);
        float a1 = __expf(m - mn);
        float a2 = __expf(m2 - mn);
        acc.x = acc.x*a1 + ax*a2;
        acc.y = acc.y*a1 + ay*a2;
        acc.z = acc.z*a1 + az*a2;
        acc.w = acc.w*a1 + aw*a2;
        l = l*a1 + l2*a2;
        m = mn;
    }
    float inv = 1.f / l;
    float4 b4 = *reinterpret_cast<const float4*>(&bias[off]);
    float4 hc;
    hc.x = fmaxf(acc.x*inv + b4.x, 0.f);
    hc.y = fmaxf(acc.y*inv + b4.y, 0.f);
    hc.z = fmaxf(acc.z*inv + b4.z, 0.f);
    hc.w = fmaxf(acc.w*inv + b4.w, 0.f);
    for (int c = q; c < 10; c += 4){
        float p = hc.x * Wlin[(off+0)*10 + c]
                + hc.y * Wlin[(off+1)*10 + c]
                + hc.z * Wlin[(off+2)*10 + c]
                + hc.w * Wlin[(off+3)*10 + c];
        p += __shfl_xor(p, 8, 64);
        p += __shfl_xor(p, 4, 64);
        p += __shfl_xor(p, 2, 64);
        p += __shfl_xor(p, 1, 64);
        if (r == 0) out[(size_t)i*10 + c] = p + blin[c];
    }
}

// ---------------- launch ----------------

extern "C" void kernel_launch(void* const* d_in, const int* in_sizes, int n_in,
                              void* d_out, int out_size, void* d_ws, size_t ws_size,
                              hipStream_t stream)
{
    const float* x    = (const float*)d_in[0];
    const int*   ei   = (const int*)  d_in[1];
    const float* Wl1  = (const float*)d_in[2];
    const float* Wr1  = (const float*)d_in[3];
    const float* att1 = (const float*)d_in[4];
    const float* b1   = (const float*)d_in[5];
    const float* Wl2  = (const float*)d_in[6];
    const float* Wr2  = (const float*)d_in[7];
    const float* att2 = (const float*)d_in[8];
    const float* b2   = (const float*)d_in[9];
    const float* Wlin = (const float*)d_in[10];
    const float* blin = (const float*)d_in[11];
    float* out = (float*)d_out;

    const int N = in_sizes[0] / 256;
    const int E = in_sizes[1] / 2;
    const int K = 256;
    const int* srcp = ei;
    const int* dstp = ei + E;

    char* ws = (char*)d_ws;
    size_t off = 0;
    auto alloc = [&](size_t bytes)->char*{
        char* p = ws + off;
        off += (bytes + 255) & ~(size_t)255;
        return p;
    };
    float* xlr1 = (float*)alloc((size_t)N*512*4);           // layer-1 GEMM out [N][512]
    float* xlr2 = (float*)alloc((size_t)N*128*4);           // layer-2 GEMM out [N][128]
    unsigned short* xh  = (unsigned short*)alloc((size_t)N*256*2);
    unsigned short* xl_ = (unsigned short*)alloc((size_t)N*256*2);
    unsigned short* h1h = (unsigned short*)alloc((size_t)N*256*2);
    unsigned short* h1l = (unsigned short*)alloc((size_t)N*256*2);
    unsigned short* bt1h = (unsigned short*)alloc((size_t)512*K*2);
    unsigned short* bt1l = (unsigned short*)alloc((size_t)512*K*2);
    unsigned short* bt2h = (unsigned short*)alloc((size_t)128*K*2);
    unsigned short* bt2l = (unsigned short*)alloc((size_t)128*K*2);
    int* rp    = (int*)alloc((size_t)(N+1)*4);
    int* cnt   = (int*)alloc((size_t)N*4);
    int* bsum  = (int*)alloc(256*4);
    int* bsumx = (int*)alloc(256*4);
    int* esrc  = (int*)alloc((size_t)E*4);
    (void)ws_size;

    const int nb = (N + 255) / 256;
    const int eb = (E + 255) / 256;

    // CSR build
    hipLaunchKernelGGL(zero_int,  dim3(nb), dim3(256), 0, stream, cnt, N);
    hipLaunchKernelGGL(hist_k,    dim3(eb), dim3(256), 0, stream, dstp, E, cnt);
    hipLaunchKernelGGL(scan1_k,   dim3(nb), dim3(256), 0, stream, cnt, N, rp, bsum);
    hipLaunchKernelGGL(scan2_k,   dim3(1),  dim3(256), 0, stream, bsum, nb, bsumx);
    hipLaunchKernelGGL(scan3_k,   dim3(nb), dim3(256), 0, stream, rp, bsumx, cnt, N, E);
    hipLaunchKernelGGL(scatter_k, dim3(eb), dim3(256), 0, stream, srcp, dstp, E, cnt, esrc);

    // conversions (overlap-friendly: independent of CSR)
    hipLaunchKernelGGL(cvt_split_k, dim3((N*256/4 + 255)/256), dim3(256), 0, stream,
                       x, xh, xl_, N*256/4);
    hipLaunchKernelGGL(cvt_w_k, dim3((512*K + 255)/256), dim3(256), 0, stream,
                       Wl1, Wr1, 256, K, bt1h, bt1l);
    hipLaunchKernelGGL(cvt_w_k, dim3((128*K + 255)/256), dim3(256), 0, stream,
                       Wl2, Wr2, 64, K, bt2h, bt2l);

    // layer 1
    hipLaunchKernelGGL(gemm_mfma, dim3(4, (N+127)/128), dim3(256), 0, stream,
                       xh, xl_, bt1h, bt1l, xlr1, N, 512, K);
    hipLaunchKernelGGL(agg1_k, dim3((N+3)/4), dim3(256), 0, stream,
                       xlr1, rp, esrc, att1, b1, h1h, h1l, N);

    // layer 2
    hipLaunchKernelGGL(gemm_mfma, dim3(1, (N+127)/128), dim3(256), 0, stream,
                       h1h, h1l, bt2h, bt2l, xlr2, N, 128, K);
    hipLaunchKernelGGL(agg2_k, dim3((N+3)/4), dim3(256), 0, stream,
                       xlr2, rp, esrc, att2, b2, Wlin, blin, out, N);
}

// Round 4
// 476.235 us; speedup vs baseline: 1.7556x; 1.0675x over previous
//
#include <hip/hip_runtime.h>
#include <hip/hip_bf16.h>
#include <hip/hip_fp16.h>
#include <math.h>

#define NEG_SLOPE 0.2f

typedef short bf16x8 __attribute__((ext_vector_type(8)));
typedef float f32x4  __attribute__((ext_vector_type(4)));

__device__ __forceinline__ unsigned short f2bf(float f){
    unsigned int u = __float_as_uint(f);
    u += 0x7fffu + ((u >> 16) & 1u);          // RNE
    return (unsigned short)(u >> 16);
}
__device__ __forceinline__ float bf2f(unsigned short h){
    return __uint_as_float(((unsigned int)h) << 16);
}
__device__ __forceinline__ void split_bf(float v, unsigned short& h, unsigned short& l){
    h = f2bf(v);
    l = f2bf(v - bf2f(h));
}
__device__ __forceinline__ float lrelu(float x){ return fmaxf(x, NEG_SLOPE * x); }

// ---------------- CSR build ----------------

__global__ void zero_int(int* __restrict__ p, int n){
    int i = blockIdx.x*256 + threadIdx.x;
    if (i < n) p[i] = 0;
}

__global__ void hist_k(const int* __restrict__ dst, int E, int* __restrict__ cnt){
    int e = blockIdx.x*256 + threadIdx.x;
    if (e < E) atomicAdd(&cnt[dst[e]], 1);
}

__global__ void scan1_k(const int* __restrict__ deg, int Nn, int* __restrict__ rp, int* __restrict__ bsum){
    __shared__ int s[256];
    int t = threadIdx.x, b = blockIdx.x;
    int i = b*256 + t;
    int v = (i < Nn) ? deg[i] : 0;
    s[t] = v;
    __syncthreads();
    #pragma unroll
    for (int d = 1; d < 256; d <<= 1){
        int u = (t >= d) ? s[t-d] : 0;
        __syncthreads();
        s[t] += u;
        __syncthreads();
    }
    if (i < Nn) rp[i] = s[t] - v;
    if (t == 255) bsum[b] = s[255];
}

__global__ void scan2_k(const int* __restrict__ bsum, int nb, int* __restrict__ bsumx){
    __shared__ int s[256];
    int t = threadIdx.x;
    int v = (t < nb) ? bsum[t] : 0;
    s[t] = v;
    __syncthreads();
    #pragma unroll
    for (int d = 1; d < 256; d <<= 1){
        int u = (t >= d) ? s[t-d] : 0;
        __syncthreads();
        s[t] += u;
        __syncthreads();
    }
    if (t < nb) bsumx[t] = s[t] - v;
}

__global__ void scan3_k(int* __restrict__ rp, const int* __restrict__ bsumx,
                        int* __restrict__ cnt, int Nn, int E){
    int b = blockIdx.x, t = threadIdx.x;
    int i = b*256 + t;
    if (i < Nn){
        int r = rp[i] + bsumx[b];
        rp[i]  = r;
        cnt[i] = r;
    }
    if (b == 0 && t == 0) rp[Nn] = E;
}

__global__ void scatter_k(const int* __restrict__ src, const int* __restrict__ dst,
                          int E, int* __restrict__ cnt, int* __restrict__ esrc){
    int e = blockIdx.x*256 + threadIdx.x;
    if (e < E){
        int d = dst[e];
        int pos = atomicAdd(&cnt[d], 1);
        esrc[pos] = src[e];
    }
}

// ---------------- conversions ----------------

__global__ void cvt_split_k(const float* __restrict__ X,
                            unsigned short* __restrict__ H, unsigned short* __restrict__ L, int n4){
    int i = blockIdx.x*256 + threadIdx.x;
    if (i >= n4) return;
    float4 v = reinterpret_cast<const float4*>(X)[i];
    unsigned short h0,h1,h2,h3,l0,l1,l2,l3;
    split_bf(v.x, h0, l0); split_bf(v.y, h1, l1);
    split_bf(v.z, h2, l2); split_bf(v.w, h3, l3);
    uint2 ph, pl;
    ph.x = (unsigned)h0 | ((unsigned)h1 << 16);
    ph.y = (unsigned)h2 | ((unsigned)h3 << 16);
    pl.x = (unsigned)l0 | ((unsigned)l1 << 16);
    pl.y = (unsigned)l2 | ((unsigned)l3 << 16);
    reinterpret_cast<uint2*>(H)[i] = ph;
    reinterpret_cast<uint2*>(L)[i] = pl;
}

// weights [K][Nw] (two of them) -> transposed split Bt[2*Nw][K] bf16 hi/lo
__global__ void cvt_w_k(const float* __restrict__ Wl, const float* __restrict__ Wr,
                        int Nw, int K,
                        unsigned short* __restrict__ Bth, unsigned short* __restrict__ Btl){
    int t = blockIdx.x*256 + threadIdx.x;
    int total = 2*Nw*K;
    if (t >= total) return;
    int k = t & (K-1);
    int n = t >> 8;                 // K == 256
    float v = (n < Nw) ? Wl[(size_t)k*Nw + n] : Wr[(size_t)k*Nw + (n - Nw)];
    unsigned short h, l;
    split_bf(v, h, l);
    Bth[t] = h; Btl[t] = l;
}

// ---------------- split-bf16 MFMA GEMM ----------------
// C = A @ B, B given as [Ntot][K]. Cols [0,Nhalf) -> fp16 xlG [M][Nhalf];
// cols [Nhalf,Ntot) -> fp32 xrB [M][Nhalf]. Tile 128x128, 4 waves, 16x16x32 bf16,
// 3 MFMAs per step: Ah*Bh + Ah*Bl + Al*Bh.
__global__ __launch_bounds__(256) void gemm_mfma(
    const unsigned short* __restrict__ Ah, const unsigned short* __restrict__ Al,
    const unsigned short* __restrict__ Bh, const unsigned short* __restrict__ Bl,
    __half* __restrict__ xlG, float* __restrict__ xrB,
    int M, int Ntot, int K)
{
    __shared__ __align__(16) unsigned short sAh[128*40];
    __shared__ __align__(16) unsigned short sAl[128*40];
    __shared__ __align__(16) unsigned short sBh[128*40];
    __shared__ __align__(16) unsigned short sBl[128*40];

    int t = threadIdx.x;
    int lane = t & 63, wave = t >> 6;
    int wm = (wave >> 1) * 64, wn = (wave & 1) * 64;
    int m0 = blockIdx.y * 128, n0 = blockIdx.x * 128;
    int lm = lane & 15, kq = lane >> 4;
    int Nhalf = Ntot >> 1;

    f32x4 acc[4][4] = {};

    for (int kc = 0; kc < K; kc += 32){
        __syncthreads();
        #pragma unroll
        for (int it = 0; it < 2; ++it){
            int idx = t + 256*it;
            int r = idx >> 2, s = (idx & 3) * 8;
            size_t ga = (size_t)(m0 + r) * K + kc + s;
            uint4 vh = make_uint4(0u,0u,0u,0u), vl = vh;
            if (m0 + r < M){
                vh = *reinterpret_cast<const uint4*>(Ah + ga);
                vl = *reinterpret_cast<const uint4*>(Al + ga);
            }
            *reinterpret_cast<uint4*>(sAh + r*40 + s) = vh;
            *reinterpret_cast<uint4*>(sAl + r*40 + s) = vl;
            size_t gb = (size_t)(n0 + r) * K + kc + s;
            *reinterpret_cast<uint4*>(sBh + r*40 + s) = *reinterpret_cast<const uint4*>(Bh + gb);
            *reinterpret_cast<uint4*>(sBl + r*40 + s) = *reinterpret_cast<const uint4*>(Bl + gb);
        }
        __syncthreads();

        bf16x8 fah[4], fal[4], fbh[4], fbl[4];
        #pragma unroll
        for (int i = 0; i < 4; ++i){
            int ar = wm + i*16 + lm;
            fah[i] = *reinterpret_cast<const bf16x8*>(sAh + ar*40 + kq*8);
            fal[i] = *reinterpret_cast<const bf16x8*>(sAl + ar*40 + kq*8);
            int br = wn + i*16 + lm;
            fbh[i] = *reinterpret_cast<const bf16x8*>(sBh + br*40 + kq*8);
            fbl[i] = *reinterpret_cast<const bf16x8*>(sBl + br*40 + kq*8);
        }
        #pragma unroll
        for (int i = 0; i < 4; ++i)
            #pragma unroll
            for (int j = 0; j < 4; ++j){
                acc[i][j] = __builtin_amdgcn_mfma_f32_16x16x32_bf16(fah[i], fbh[j], acc[i][j], 0, 0, 0);
                acc[i][j] = __builtin_amdgcn_mfma_f32_16x16x32_bf16(fah[i], fbl[j], acc[i][j], 0, 0, 0);
                acc[i][j] = __builtin_amdgcn_mfma_f32_16x16x32_bf16(fal[i], fbh[j], acc[i][j], 0, 0, 0);
            }
    }

    #pragma unroll
    for (int i = 0; i < 4; ++i){
        #pragma unroll
        for (int r = 0; r < 4; ++r){
            int m = m0 + wm + i*16 + kq*4 + r;
            if (m < M){
                #pragma unroll
                for (int j = 0; j < 4; ++j){
                    int nc = n0 + wn + j*16 + lm;
                    float v = acc[i][j][r];
                    if (nc < Nhalf) xlG[(size_t)m*Nhalf + nc] = __float2half(v);
                    else            xrB[(size_t)m*Nhalf + nc - Nhalf] = v;
                }
            }
        }
    }
}

// ---------------- layer-1 aggregation: wave per node, lane = 4 channels (fp16 gather) ----------------
__global__ __launch_bounds__(256) void agg1_k(
    const __half* __restrict__ xlG, const float* __restrict__ xrB,
    const int* __restrict__ rp, const int* __restrict__ esrc,
    const float* __restrict__ att, const float* __restrict__ bias,
    unsigned short* __restrict__ h1h, unsigned short* __restrict__ h1l, int Nn)
{
    int wave = threadIdx.x >> 6, lane = threadIdx.x & 63;
    int i = blockIdx.x*4 + wave;
    if (i >= Nn) return;
    int off = lane*4;
    float4 xr4 = *reinterpret_cast<const float4*>(&xrB[(size_t)i*256 + off]);
    float4 at4 = *reinterpret_cast<const float4*>(&att[off]);
    int beg = rp[i], nE = rp[i+1] - beg;

    float l = 0.f;
    float4 acc = make_float4(0.f,0.f,0.f,0.f);

    auto proc = [&](uint2 raw){
        union { uint2 u; __half2 h[2]; } cv; cv.u = raw;
        float2 f01 = __half22float2(cv.h[0]);
        float2 f23 = __half22float2(cv.h[1]);
        float sc = lrelu(f01.x + xr4.x) * at4.x
                 + lrelu(f01.y + xr4.y) * at4.y
                 + lrelu(f23.x + xr4.z) * at4.z
                 + lrelu(f23.y + xr4.w) * at4.w;
        sc += __shfl_xor(sc, 8, 64);
        sc += __shfl_xor(sc, 4, 64);
        sc += __shfl_xor(sc, 2, 64);
        sc += __shfl_xor(sc, 1, 64);
        float w = __expf(sc);
        l += w;
        acc.x = fmaf(w, f01.x, acc.x);
        acc.y = fmaf(w, f01.y, acc.y);
        acc.z = fmaf(w, f23.x, acc.z);
        acc.w = fmaf(w, f23.y, acc.w);
    };

    uint2 sraw = *reinterpret_cast<const uint2*>(xlG + (size_t)i*256 + off);
    uint2 raw;
    if (nE > 0){
        int sn0 = esrc[beg];
        raw = *reinterpret_cast<const uint2*>(xlG + (size_t)sn0*256 + off);
    }
    proc(sraw);                               // self-loop
    for (int j = 0; j < nE; ++j){
        int jn = (j+1 < nE) ? (j+1) : (nE-1);
        int snn = esrc[beg + jn];
        uint2 rawn = *reinterpret_cast<const uint2*>(xlG + (size_t)snn*256 + off);
        proc(raw);
        raw = rawn;
    }

    float inv = 1.f / l;
    float4 b4 = *reinterpret_cast<const float4*>(&bias[off]);
    float o0 = fmaxf(acc.x*inv + b4.x, 0.f);
    float o1 = fmaxf(acc.y*inv + b4.y, 0.f);
    float o2 = fmaxf(acc.z*inv + b4.z, 0.f);
    float o3 = fmaxf(acc.w*inv + b4.w, 0.f);
    unsigned short h0,h1,h2,h3,l0,l1,l2,l3;
    split_bf(o0,h0,l0); split_bf(o1,h1,l1); split_bf(o2,h2,l2); split_bf(o3,h3,l3);
    uint2 ph, pl;
    ph.x = (unsigned)h0 | ((unsigned)h1 << 16);
    ph.y = (unsigned)h2 | ((unsigned)h3 << 16);
    pl.x = (unsigned)l0 | ((unsigned)l1 << 16);
    pl.y = (unsigned)l2 | ((unsigned)l3 << 16);
    *reinterpret_cast<uint2*>(&h1h[(size_t)i*256 + off]) = ph;
    *reinterpret_cast<uint2*>(&h1l[(size_t)i*256 + off]) = pl;
}

// ---------------- layer-2 aggregation + final linear: wave per node, 4 quarters (fp16 gather) ----------------
__global__ __launch_bounds__(256) void agg2_k(
    const __half* __restrict__ xlG, const float* __restrict__ xrB,
    const int* __restrict__ rp, const int* __restrict__ esrc,
    const float* __restrict__ att, const float* __restrict__ bias,
    const float* __restrict__ Wlin, const float* __restrict__ blin,
    float* __restrict__ out, int Nn)
{
    int wave = threadIdx.x >> 6, lane = threadIdx.x & 63;
    int i = blockIdx.x*4 + wave;
    if (i >= Nn) return;
    int q = lane >> 4, r = lane & 15;
    int off = r*4;
    float4 xr4 = *reinterpret_cast<const float4*>(&xrB[(size_t)i*64 + off]);
    float4 at4 = *reinterpret_cast<const float4*>(&att[off]);
    int beg = rp[i], nE = rp[i+1] - beg;
    int nItems = nE + 1;

    float l = 0.f;
    float4 acc = make_float4(0.f,0.f,0.f,0.f);
    for (int j = q; j < nItems; j += 4){
        uint2 raw;
        if (j == 0){
            raw = *reinterpret_cast<const uint2*>(xlG + (size_t)i*64 + off);
        } else {
            int sn = esrc[beg + j - 1];
            raw = *reinterpret_cast<const uint2*>(xlG + (size_t)sn*64 + off);
        }
        union { uint2 u; __half2 h[2]; } cv; cv.u = raw;
        float2 f01 = __half22float2(cv.h[0]);
        float2 f23 = __half22float2(cv.h[1]);
        float sc = lrelu(f01.x + xr4.x) * at4.x
                 + lrelu(f01.y + xr4.y) * at4.y
                 + lrelu(f23.x + xr4.z) * at4.z
                 + lrelu(f23.y + xr4.w) * at4.w;
        sc += __shfl_xor(sc, 8, 64);
        sc += __shfl_xor(sc, 4, 64);
        sc += __shfl_xor(sc, 2, 64);
        sc += __shfl_xor(sc, 1, 64);
        float w = __expf(sc);
        l += w;
        acc.x = fmaf(w, f01.x, acc.x);
        acc.y = fmaf(w, f01.y, acc.y);
        acc.z = fmaf(w, f23.x, acc.z);
        acc.w = fmaf(w, f23.y, acc.w);
    }
    // merge the 4 quarters (plain sums; no max tracking needed)
    #pragma unroll
    for (int s = 16; s <= 32; s <<= 1){
        l     += __shfl_xor(l, s, 64);
        acc.x += __shfl_xor(acc.x, s, 64);
        acc.y += __shfl_xor(acc.y, s, 64);
        acc.z += __shfl_xor(acc.z, s, 64);
        acc.w += __shfl_xor(acc.w, s, 64);
    }
    float inv = 1.f / l;
    float4 b4 = *reinterpret_cast<const float4*>(&bias[off]);
    float4 hc;
    hc.x = fmaxf(acc.x*inv + b4.x, 0.f);
    hc.y = fmaxf(acc.y*inv + b4.y, 0.f);
    hc.z = fmaxf(acc.z*inv + b4.z, 0.f);
    hc.w = fmaxf(acc.w*inv + b4.w, 0.f);
    for (int c = q; c < 10; c += 4){
        float p = hc.x * Wlin[(off+0)*10 + c]
                + hc.y * Wlin[(off+1)*10 + c]
                + hc.z * Wlin[(off+2)*10 + c]
                + hc.w * Wlin[(off+3)*10 + c];
        p += __shfl_xor(p, 8, 64);
        p += __shfl_xor(p, 4, 64);
        p += __shfl_xor(p, 2, 64);
        p += __shfl_xor(p, 1, 64);
        if (r == 0) out[(size_t)i*10 + c] = p + blin[c];
    }
}

// ---------------- launch ----------------

extern "C" void kernel_launch(void* const* d_in, const int* in_sizes, int n_in,
                              void* d_out, int out_size, void* d_ws, size_t ws_size,
                              hipStream_t stream)
{
    const float* x    = (const float*)d_in[0];
    const int*   ei   = (const int*)  d_in[1];
    const float* Wl1  = (const float*)d_in[2];
    const float* Wr1  = (const float*)d_in[3];
    const float* att1 = (const float*)d_in[4];
    const float* b1   = (const float*)d_in[5];
    const float* Wl2  = (const float*)d_in[6];
    const float* Wr2  = (const float*)d_in[7];
    const float* att2 = (const float*)d_in[8];
    const float* b2   = (const float*)d_in[9];
    const float* Wlin = (const float*)d_in[10];
    const float* blin = (const float*)d_in[11];
    float* out = (float*)d_out;

    const int N = in_sizes[0] / 256;
    const int E = in_sizes[1] / 2;
    const int K = 256;
    const int* srcp = ei;
    const int* dstp = ei + E;

    char* ws = (char*)d_ws;
    size_t off = 0;
    auto alloc = [&](size_t bytes)->char*{
        char* p = ws + off;
        off += (bytes + 255) & ~(size_t)255;
        return p;
    };
    __half* xlG1 = (__half*)alloc((size_t)N*256*2);   // layer-1 xl, fp16
    float*  xr1  = (float*) alloc((size_t)N*256*4);   // layer-1 xr, fp32
    __half* xlG2 = (__half*)alloc((size_t)N*64*2);    // layer-2 xl, fp16
    float*  xr2  = (float*) alloc((size_t)N*64*4);    // layer-2 xr, fp32
    unsigned short* xh  = (unsigned short*)alloc((size_t)N*256*2);
    unsigned short* xl_ = (unsigned short*)alloc((size_t)N*256*2);
    unsigned short* h1h = (unsigned short*)alloc((size_t)N*256*2);
    unsigned short* h1l = (unsigned short*)alloc((size_t)N*256*2);
    unsigned short* bt1h = (unsigned short*)alloc((size_t)512*K*2);
    unsigned short* bt1l = (unsigned short*)alloc((size_t)512*K*2);
    unsigned short* bt2h = (unsigned short*)alloc((size_t)128*K*2);
    unsigned short* bt2l = (unsigned short*)alloc((size_t)128*K*2);
    int* rp    = (int*)alloc((size_t)(N+1)*4);
    int* cnt   = (int*)alloc((size_t)N*4);
    int* bsum  = (int*)alloc(256*4);
    int* bsumx = (int*)alloc(256*4);
    int* esrc  = (int*)alloc((size_t)E*4);
    (void)ws_size;

    const int nb = (N + 255) / 256;
    const int eb = (E + 255) / 256;

    // CSR build
    hipLaunchKernelGGL(zero_int,  dim3(nb), dim3(256), 0, stream, cnt, N);
    hipLaunchKernelGGL(hist_k,    dim3(eb), dim3(256), 0, stream, dstp, E, cnt);
    hipLaunchKernelGGL(scan1_k,   dim3(nb), dim3(256), 0, stream, cnt, N, rp, bsum);
    hipLaunchKernelGGL(scan2_k,   dim3(1),  dim3(256), 0, stream, bsum, nb, bsumx);
    hipLaunchKernelGGL(scan3_k,   dim3(nb), dim3(256), 0, stream, rp, bsumx, cnt, N, E);
    hipLaunchKernelGGL(scatter_k, dim3(eb), dim3(256), 0, stream, srcp, dstp, E, cnt, esrc);

    // conversions
    hipLaunchKernelGGL(cvt_split_k, dim3((N*256/4 + 255)/256), dim3(256), 0, stream,
                       x, xh, xl_, N*256/4);
    hipLaunchKernelGGL(cvt_w_k, dim3((512*K + 255)/256), dim3(256), 0, stream,
                       Wl1, Wr1, 256, K, bt1h, bt1l);
    hipLaunchKernelGGL(cvt_w_k, dim3((128*K + 255)/256), dim3(256), 0, stream,
                       Wl2, Wr2, 64, K, bt2h, bt2l);

    // layer 1
    hipLaunchKernelGGL(gemm_mfma, dim3(4, (N+127)/128), dim3(256), 0, stream,
                       xh, xl_, bt1h, bt1l, xlG1, xr1, N, 512, K);
    hipLaunchKernelGGL(agg1_k, dim3((N+3)/4), dim3(256), 0, stream,
                       xlG1, xr1, rp, esrc, att1, b1, h1h, h1l, N);

    // layer 2
    hipLaunchKernelGGL(gemm_mfma, dim3(1, (N+127)/128), dim3(256), 0, stream,
                       h1h, h1l, bt2h, bt2l, xlG2, xr2, N, 128, K);
    hipLaunchKernelGGL(agg2_k, dim3((N+3)/4), dim3(256), 0, stream,
                       xlG2, xr2, rp, esrc, att2, b2, Wlin, blin, out, N);
}

// Round 5
// 461.780 us; speedup vs baseline: 1.8106x; 1.0313x over previous
//
#include <hip/hip_runtime.h>
#include <hip/hip_bf16.h>
#include <hip/hip_fp16.h>
#include <math.h>

#define NEG_SLOPE 0.2f

typedef short bf16x8 __attribute__((ext_vector_type(8)));
typedef float f32x4  __attribute__((ext_vector_type(4)));
typedef _Float16 h2v __attribute__((ext_vector_type(2)));

union U2 { uint2 u; h2v h[2]; };

__device__ __forceinline__ unsigned short f2bf(float f){
    unsigned int u = __float_as_uint(f);
    u += 0x7fffu + ((u >> 16) & 1u);          // RNE
    return (unsigned short)(u >> 16);
}
__device__ __forceinline__ float bf2f(unsigned short h){
    return __uint_as_float(((unsigned int)h) << 16);
}
__device__ __forceinline__ void split_bf(float v, unsigned short& h, unsigned short& l){
    h = f2bf(v);
    l = f2bf(v - bf2f(h));
}

__device__ __forceinline__ h2v pk_lrelu(h2v s){
    h2v k = { (_Float16)NEG_SLOPE, (_Float16)NEG_SLOPE };
    return __builtin_elementwise_max(s, s * k);
}

__device__ __forceinline__ float dot4_lrelu(h2v v01, h2v v23, h2v x01, h2v x23,
                                            h2v a01, h2v a23){
    h2v t01 = pk_lrelu(v01 + x01);
    h2v t23 = pk_lrelu(v23 + x23);
#if __has_builtin(__builtin_amdgcn_fdot2)
    return __builtin_amdgcn_fdot2(t01, a01,
           __builtin_amdgcn_fdot2(t23, a23, 0.f, false), false);
#else
    return (float)t01[0]*(float)a01[0] + (float)t01[1]*(float)a01[1]
         + (float)t23[0]*(float)a23[0] + (float)t23[1]*(float)a23[1];
#endif
}

// ---------------- CSR build ----------------

__global__ void zero_int(int* __restrict__ p, int n){
    int i = blockIdx.x*256 + threadIdx.x;
    if (i < n) p[i] = 0;
}

__global__ void hist_k(const int* __restrict__ dst, int E, int* __restrict__ cnt){
    int e = blockIdx.x*256 + threadIdx.x;
    if (e < E) atomicAdd(&cnt[dst[e]], 1);
}

__global__ void scan1_k(const int* __restrict__ deg, int Nn, int* __restrict__ rp, int* __restrict__ bsum){
    __shared__ int s[256];
    int t = threadIdx.x, b = blockIdx.x;
    int i = b*256 + t;
    int v = (i < Nn) ? deg[i] : 0;
    s[t] = v;
    __syncthreads();
    #pragma unroll
    for (int d = 1; d < 256; d <<= 1){
        int u = (t >= d) ? s[t-d] : 0;
        __syncthreads();
        s[t] += u;
        __syncthreads();
    }
    if (i < Nn) rp[i] = s[t] - v;
    if (t == 255) bsum[b] = s[255];
}

__global__ void scan2_k(const int* __restrict__ bsum, int nb, int* __restrict__ bsumx){
    __shared__ int s[256];
    int t = threadIdx.x;
    int v = (t < nb) ? bsum[t] : 0;
    s[t] = v;
    __syncthreads();
    #pragma unroll
    for (int d = 1; d < 256; d <<= 1){
        int u = (t >= d) ? s[t-d] : 0;
        __syncthreads();
        s[t] += u;
        __syncthreads();
    }
    if (t < nb) bsumx[t] = s[t] - v;
}

__global__ void scan3_k(int* __restrict__ rp, const int* __restrict__ bsumx,
                        int* __restrict__ cnt, int Nn, int E){
    int b = blockIdx.x, t = threadIdx.x;
    int i = b*256 + t;
    if (i < Nn){
        int r = rp[i] + bsumx[b];
        rp[i]  = r;
        cnt[i] = r;
    }
    if (b == 0 && t == 0) rp[Nn] = E;
}

__global__ void scatter_k(const int* __restrict__ src, const int* __restrict__ dst,
                          int E, int* __restrict__ cnt, int* __restrict__ esrc){
    int e = blockIdx.x*256 + threadIdx.x;
    if (e < E){
        int d = dst[e];
        int pos = atomicAdd(&cnt[d], 1);
        esrc[pos] = src[e];
    }
}

// ---------------- conversions ----------------

__global__ void cvt_split_k(const float* __restrict__ X,
                            unsigned short* __restrict__ H, unsigned short* __restrict__ L, int n4){
    int i = blockIdx.x*256 + threadIdx.x;
    if (i >= n4) return;
    float4 v = reinterpret_cast<const float4*>(X)[i];
    unsigned short h0,h1,h2,h3,l0,l1,l2,l3;
    split_bf(v.x, h0, l0); split_bf(v.y, h1, l1);
    split_bf(v.z, h2, l2); split_bf(v.w, h3, l3);
    uint2 ph, pl;
    ph.x = (unsigned)h0 | ((unsigned)h1 << 16);
    ph.y = (unsigned)h2 | ((unsigned)h3 << 16);
    pl.x = (unsigned)l0 | ((unsigned)l1 << 16);
    pl.y = (unsigned)l2 | ((unsigned)l3 << 16);
    reinterpret_cast<uint2*>(H)[i] = ph;
    reinterpret_cast<uint2*>(L)[i] = pl;
}

// weights [K][Nw] (two of them) -> transposed split Bt[2*Nw][K] bf16 hi/lo
__global__ void cvt_w_k(const float* __restrict__ Wl, const float* __restrict__ Wr,
                        int Nw, int K,
                        unsigned short* __restrict__ Bth, unsigned short* __restrict__ Btl){
    int t = blockIdx.x*256 + threadIdx.x;
    int total = 2*Nw*K;
    if (t >= total) return;
    int k = t & (K-1);
    int n = t >> 8;                 // K == 256
    float v = (n < Nw) ? Wl[(size_t)k*Nw + n] : Wr[(size_t)k*Nw + (n - Nw)];
    unsigned short h, l;
    split_bf(v, h, l);
    Bth[t] = h; Btl[t] = l;
}

// att1 (256), att2 (64) -> fp16
__global__ void cvt_att_k(const float* __restrict__ a1, const float* __restrict__ a2,
                          _Float16* __restrict__ o1, _Float16* __restrict__ o2){
    int t = threadIdx.x;
    o1[t] = (_Float16)a1[t];
    if (t < 64) o2[t] = (_Float16)a2[t];
}

// ---------------- split-bf16 MFMA GEMM ----------------
// C = A @ B (B given as [Ntot][K]); C written fp16 [M][Ntot].
// Tile 128x128, 4 waves, 16x16x32 bf16, 3 MFMAs/step (Ah*Bh + Ah*Bl + Al*Bh).
__global__ __launch_bounds__(256) void gemm_mfma(
    const unsigned short* __restrict__ Ah, const unsigned short* __restrict__ Al,
    const unsigned short* __restrict__ Bh, const unsigned short* __restrict__ Bl,
    _Float16* __restrict__ Cout, int M, int Ntot, int K)
{
    __shared__ __align__(16) unsigned short sAh[128*40];
    __shared__ __align__(16) unsigned short sAl[128*40];
    __shared__ __align__(16) unsigned short sBh[128*40];
    __shared__ __align__(16) unsigned short sBl[128*40];

    int t = threadIdx.x;
    int lane = t & 63, wave = t >> 6;
    int wm = (wave >> 1) * 64, wn = (wave & 1) * 64;
    int m0 = blockIdx.y * 128, n0 = blockIdx.x * 128;
    int lm = lane & 15, kq = lane >> 4;

    f32x4 acc[4][4] = {};

    for (int kc = 0; kc < K; kc += 32){
        __syncthreads();
        #pragma unroll
        for (int it = 0; it < 2; ++it){
            int idx = t + 256*it;
            int r = idx >> 2, s = (idx & 3) * 8;
            size_t ga = (size_t)(m0 + r) * K + kc + s;
            uint4 vh = make_uint4(0u,0u,0u,0u), vl = vh;
            if (m0 + r < M){
                vh = *reinterpret_cast<const uint4*>(Ah + ga);
                vl = *reinterpret_cast<const uint4*>(Al + ga);
            }
            *reinterpret_cast<uint4*>(sAh + r*40 + s) = vh;
            *reinterpret_cast<uint4*>(sAl + r*40 + s) = vl;
            size_t gb = (size_t)(n0 + r) * K + kc + s;
            *reinterpret_cast<uint4*>(sBh + r*40 + s) = *reinterpret_cast<const uint4*>(Bh + gb);
            *reinterpret_cast<uint4*>(sBl + r*40 + s) = *reinterpret_cast<const uint4*>(Bl + gb);
        }
        __syncthreads();

        bf16x8 fah[4], fal[4], fbh[4], fbl[4];
        #pragma unroll
        for (int i = 0; i < 4; ++i){
            int ar = wm + i*16 + lm;
            fah[i] = *reinterpret_cast<const bf16x8*>(sAh + ar*40 + kq*8);
            fal[i] = *reinterpret_cast<const bf16x8*>(sAl + ar*40 + kq*8);
            int br = wn + i*16 + lm;
            fbh[i] = *reinterpret_cast<const bf16x8*>(sBh + br*40 + kq*8);
            fbl[i] = *reinterpret_cast<const bf16x8*>(sBl + br*40 + kq*8);
        }
        #pragma unroll
        for (int i = 0; i < 4; ++i)
            #pragma unroll
            for (int j = 0; j < 4; ++j){
                acc[i][j] = __builtin_amdgcn_mfma_f32_16x16x32_bf16(fah[i], fbh[j], acc[i][j], 0, 0, 0);
                acc[i][j] = __builtin_amdgcn_mfma_f32_16x16x32_bf16(fah[i], fbl[j], acc[i][j], 0, 0, 0);
                acc[i][j] = __builtin_amdgcn_mfma_f32_16x16x32_bf16(fal[i], fbh[j], acc[i][j], 0, 0, 0);
            }
    }

    #pragma unroll
    for (int i = 0; i < 4; ++i){
        #pragma unroll
        for (int r = 0; r < 4; ++r){
            int m = m0 + wm + i*16 + kq*4 + r;
            if (m < M){
                #pragma unroll
                for (int j = 0; j < 4; ++j){
                    int nc = n0 + wn + j*16 + lm;
                    Cout[(size_t)m*Ntot + nc] = (_Float16)acc[i][j][r];
                }
            }
        }
    }
}

// ---------------- layer-1 aggregation: wave per node, lane = 4 channels (all-fp16 row) ----------------
// xlr [N][512] fp16: cols 0..255 = xl, 256..511 = xr.
__global__ __launch_bounds__(256) void agg1_k(
    const _Float16* __restrict__ xlr,
    const int* __restrict__ rp, const int* __restrict__ esrc,
    const _Float16* __restrict__ attH, const float* __restrict__ bias,
    unsigned short* __restrict__ h1h, unsigned short* __restrict__ h1l, int Nn)
{
    int wave = threadIdx.x >> 6, lane = threadIdx.x & 63;
    int i = blockIdx.x*4 + wave;
    if (i >= Nn) return;
    int off = lane*4;
    U2 xr; xr.u = *reinterpret_cast<const uint2*>(xlr + (size_t)i*512 + 256 + off);
    U2 at; at.u = *reinterpret_cast<const uint2*>(attH + off);
    int beg = rp[i], nE = rp[i+1] - beg;

    float l = 0.f;
    float4 acc = make_float4(0.f,0.f,0.f,0.f);

    auto proc = [&](uint2 rawu){
        U2 cv; cv.u = rawu;
        float sc = dot4_lrelu(cv.h[0], cv.h[1], xr.h[0], xr.h[1], at.h[0], at.h[1]);
        sc += __shfl_xor(sc, 8, 64);
        sc += __shfl_xor(sc, 4, 64);
        sc += __shfl_xor(sc, 2, 64);
        sc += __shfl_xor(sc, 1, 64);
        float w = __expf(sc);
        l += w;
        acc.x = fmaf(w, (float)cv.h[0][0], acc.x);
        acc.y = fmaf(w, (float)cv.h[0][1], acc.y);
        acc.z = fmaf(w, (float)cv.h[1][0], acc.z);
        acc.w = fmaf(w, (float)cv.h[1][1], acc.w);
    };

    uint2 sraw = *reinterpret_cast<const uint2*>(xlr + (size_t)i*512 + off);
    uint2 raw;
    if (nE > 0){
        int sn0 = esrc[beg];
        raw = *reinterpret_cast<const uint2*>(xlr + (size_t)sn0*512 + off);
    }
    proc(sraw);                               // self-loop
    for (int j = 0; j < nE; ++j){
        int jn = (j+1 < nE) ? (j+1) : (nE-1);
        int snn = esrc[beg + jn];
        uint2 rawn = *reinterpret_cast<const uint2*>(xlr + (size_t)snn*512 + off);
        proc(raw);
        raw = rawn;
    }

    float inv = 1.f / l;
    float4 b4 = *reinterpret_cast<const float4*>(&bias[off]);
    float o0 = fmaxf(acc.x*inv + b4.x, 0.f);
    float o1 = fmaxf(acc.y*inv + b4.y, 0.f);
    float o2 = fmaxf(acc.z*inv + b4.z, 0.f);
    float o3 = fmaxf(acc.w*inv + b4.w, 0.f);
    unsigned short h0,h1,h2,h3,l0,l1,l2,l3;
    split_bf(o0,h0,l0); split_bf(o1,h1,l1); split_bf(o2,h2,l2); split_bf(o3,h3,l3);
    uint2 ph, pl;
    ph.x = (unsigned)h0 | ((unsigned)h1 << 16);
    ph.y = (unsigned)h2 | ((unsigned)h3 << 16);
    pl.x = (unsigned)l0 | ((unsigned)l1 << 16);
    pl.y = (unsigned)l2 | ((unsigned)l3 << 16);
    *reinterpret_cast<uint2*>(&h1h[(size_t)i*256 + off]) = ph;
    *reinterpret_cast<uint2*>(&h1l[(size_t)i*256 + off]) = pl;
}

// ---------------- layer-2 aggregation + final linear: wave per node, 4 quarters ----------------
// xlr [N][128] fp16: cols 0..63 = xl, 64..127 = xr.
__global__ __launch_bounds__(256) void agg2_k(
    const _Float16* __restrict__ xlr,
    const int* __restrict__ rp, const int* __restrict__ esrc,
    const _Float16* __restrict__ attH, const float* __restrict__ bias,
    const float* __restrict__ Wlin, const float* __restrict__ blin,
    float* __restrict__ out, int Nn)
{
    int wave = threadIdx.x >> 6, lane = threadIdx.x & 63;
    int i = blockIdx.x*4 + wave;
    if (i >= Nn) return;
    int q = lane >> 4, r = lane & 15;
    int off = r*4;
    U2 xr; xr.u = *reinterpret_cast<const uint2*>(xlr + (size_t)i*128 + 64 + off);
    U2 at; at.u = *reinterpret_cast<const uint2*>(attH + off);
    int beg = rp[i], nE = rp[i+1] - beg;
    int nItems = nE + 1;

    float l = 0.f;
    float4 acc = make_float4(0.f,0.f,0.f,0.f);
    for (int j = q; j < nItems; j += 4){
        uint2 rawu;
        if (j == 0){
            rawu = *reinterpret_cast<const uint2*>(xlr + (size_t)i*128 + off);
        } else {
            int sn = esrc[beg + j - 1];
            rawu = *reinterpret_cast<const uint2*>(xlr + (size_t)sn*128 + off);
        }
        U2 cv; cv.u = rawu;
        float sc = dot4_lrelu(cv.h[0], cv.h[1], xr.h[0], xr.h[1], at.h[0], at.h[1]);
        sc += __shfl_xor(sc, 8, 64);
        sc += __shfl_xor(sc, 4, 64);
        sc += __shfl_xor(sc, 2, 64);
        sc += __shfl_xor(sc, 1, 64);
        float w = __expf(sc);
        l += w;
        acc.x = fmaf(w, (float)cv.h[0][0], acc.x);
        acc.y = fmaf(w, (float)cv.h[0][1], acc.y);
        acc.z = fmaf(w, (float)cv.h[1][0], acc.z);
        acc.w = fmaf(w, (float)cv.h[1][1], acc.w);
    }
    #pragma unroll
    for (int s = 16; s <= 32; s <<= 1){
        l     += __shfl_xor(l, s, 64);
        acc.x += __shfl_xor(acc.x, s, 64);
        acc.y += __shfl_xor(acc.y, s, 64);
        acc.z += __shfl_xor(acc.z, s, 64);
        acc.w += __shfl_xor(acc.w, s, 64);
    }
    float inv = 1.f / l;
    float4 b4 = *reinterpret_cast<const float4*>(&bias[off]);
    float4 hc;
    hc.x = fmaxf(acc.x*inv + b4.x, 0.f);
    hc.y = fmaxf(acc.y*inv + b4.y, 0.f);
    hc.z = fmaxf(acc.z*inv + b4.z, 0.f);
    hc.w = fmaxf(acc.w*inv + b4.w, 0.f);
    for (int c = q; c < 10; c += 4){
        float p = hc.x * Wlin[(off+0)*10 + c]
                + hc.y * Wlin[(off+1)*10 + c]
                + hc.z * Wlin[(off+2)*10 + c]
                + hc.w * Wlin[(off+3)*10 + c];
        p += __shfl_xor(p, 8, 64);
        p += __shfl_xor(p, 4, 64);
        p += __shfl_xor(p, 2, 64);
        p += __shfl_xor(p, 1, 64);
        if (r == 0) out[(size_t)i*10 + c] = p + blin[c];
    }
}

// ---------------- launch ----------------

extern "C" void kernel_launch(void* const* d_in, const int* in_sizes, int n_in,
                              void* d_out, int out_size, void* d_ws, size_t ws_size,
                              hipStream_t stream)
{
    const float* x    = (const float*)d_in[0];
    const int*   ei   = (const int*)  d_in[1];
    const float* Wl1  = (const float*)d_in[2];
    const float* Wr1  = (const float*)d_in[3];
    const float* att1 = (const float*)d_in[4];
    const float* b1   = (const float*)d_in[5];
    const float* Wl2  = (const float*)d_in[6];
    const float* Wr2  = (const float*)d_in[7];
    const float* att2 = (const float*)d_in[8];
    const float* b2   = (const float*)d_in[9];
    const float* Wlin = (const float*)d_in[10];
    const float* blin = (const float*)d_in[11];
    float* out = (float*)d_out;

    const int N = in_sizes[0] / 256;
    const int E = in_sizes[1] / 2;
    const int K = 256;
    const int* srcp = ei;
    const int* dstp = ei + E;

    char* ws = (char*)d_ws;
    size_t off = 0;
    auto alloc = [&](size_t bytes)->char*{
        char* p = ws + off;
        off += (bytes + 255) & ~(size_t)255;
        return p;
    };
    _Float16* xlr1 = (_Float16*)alloc((size_t)N*512*2);   // layer-1 xl|xr, fp16
    _Float16* xlr2 = (_Float16*)alloc((size_t)N*128*2);   // layer-2 xl|xr, fp16
    unsigned short* xh  = (unsigned short*)alloc((size_t)N*256*2);
    unsigned short* xl_ = (unsigned short*)alloc((size_t)N*256*2);
    unsigned short* h1h = (unsigned short*)alloc((size_t)N*256*2);
    unsigned short* h1l = (unsigned short*)alloc((size_t)N*256*2);
    unsigned short* bt1h = (unsigned short*)alloc((size_t)512*K*2);
    unsigned short* bt1l = (unsigned short*)alloc((size_t)512*K*2);
    unsigned short* bt2h = (unsigned short*)alloc((size_t)128*K*2);
    unsigned short* bt2l = (unsigned short*)alloc((size_t)128*K*2);
    _Float16* a1h = (_Float16*)alloc(256*2);
    _Float16* a2h = (_Float16*)alloc(64*2);
    int* rp    = (int*)alloc((size_t)(N+1)*4);
    int* cnt   = (int*)alloc((size_t)N*4);
    int* bsum  = (int*)alloc(256*4);
    int* bsumx = (int*)alloc(256*4);
    int* esrc  = (int*)alloc((size_t)E*4);
    (void)ws_size;

    const int nb = (N + 255) / 256;
    const int eb = (E + 255) / 256;

    // CSR build
    hipLaunchKernelGGL(zero_int,  dim3(nb), dim3(256), 0, stream, cnt, N);
    hipLaunchKernelGGL(hist_k,    dim3(eb), dim3(256), 0, stream, dstp, E, cnt);
    hipLaunchKernelGGL(scan1_k,   dim3(nb), dim3(256), 0, stream, cnt, N, rp, bsum);
    hipLaunchKernelGGL(scan2_k,   dim3(1),  dim3(256), 0, stream, bsum, nb, bsumx);
    hipLaunchKernelGGL(scan3_k,   dim3(nb), dim3(256), 0, stream, rp, bsumx, cnt, N, E);
    hipLaunchKernelGGL(scatter_k, dim3(eb), dim3(256), 0, stream, srcp, dstp, E, cnt, esrc);

    // conversions
    hipLaunchKernelGGL(cvt_split_k, dim3((N*256/4 + 255)/256), dim3(256), 0, stream,
                       x, xh, xl_, N*256/4);
    hipLaunchKernelGGL(cvt_w_k, dim3((512*K + 255)/256), dim3(256), 0, stream,
                       Wl1, Wr1, 256, K, bt1h, bt1l);
    hipLaunchKernelGGL(cvt_w_k, dim3((128*K + 255)/256), dim3(256), 0, stream,
                       Wl2, Wr2, 64, K, bt2h, bt2l);
    hipLaunchKernelGGL(cvt_att_k, dim3(1), dim3(256), 0, stream, att1, att2, a1h, a2h);

    // layer 1
    hipLaunchKernelGGL(gemm_mfma, dim3(4, (N+127)/128), dim3(256), 0, stream,
                       xh, xl_, bt1h, bt1l, xlr1, N, 512, K);
    hipLaunchKernelGGL(agg1_k, dim3((N+3)/4), dim3(256), 0, stream,
                       xlr1, rp, esrc, a1h, b1, h1h, h1l, N);

    // layer 2
    hipLaunchKernelGGL(gemm_mfma, dim3(1, (N+127)/128), dim3(256), 0, stream,
                       h1h, h1l, bt2h, bt2l, xlr2, N, 128, K);
    hipLaunchKernelGGL(agg2_k, dim3((N+3)/4), dim3(256), 0, stream,
                       xlr2, rp, esrc, a2h, b2, Wlin, blin, out, N);
}

// Round 6
// 428.438 us; speedup vs baseline: 1.9515x; 1.0778x over previous
//
#include <hip/hip_runtime.h>
#include <hip/hip_bf16.h>
#include <hip/hip_fp16.h>
#include <math.h>

#define NEG_SLOPE 0.2f

typedef _Float16 f16x8 __attribute__((ext_vector_type(8)));
typedef float f32x4  __attribute__((ext_vector_type(4)));
typedef _Float16 h2v __attribute__((ext_vector_type(2)));

union U2 { uint2 u; h2v h[2]; };

__device__ __forceinline__ h2v pk_lrelu(h2v s){
    h2v k = { (_Float16)NEG_SLOPE, (_Float16)NEG_SLOPE };
    return __builtin_elementwise_max(s, s * k);
}

__device__ __forceinline__ float dot4_lrelu(h2v v01, h2v v23, h2v x01, h2v x23,
                                            h2v a01, h2v a23){
    h2v t01 = pk_lrelu(v01 + x01);
    h2v t23 = pk_lrelu(v23 + x23);
#if __has_builtin(__builtin_amdgcn_fdot2)
    return __builtin_amdgcn_fdot2(t01, a01,
           __builtin_amdgcn_fdot2(t23, a23, 0.f, false), false);
#else
    return (float)t01[0]*(float)a01[0] + (float)t01[1]*(float)a01[1]
         + (float)t23[0]*(float)a23[0] + (float)t23[1]*(float)a23[1];
#endif
}

// ---------------- CSR build ----------------

__global__ void zero_int(int* __restrict__ p, int n){
    int i = blockIdx.x*256 + threadIdx.x;
    if (i < n) p[i] = 0;
}

__global__ void hist_k(const int* __restrict__ dst, int E, int* __restrict__ cnt){
    int e = blockIdx.x*256 + threadIdx.x;
    if (e < E) atomicAdd(&cnt[dst[e]], 1);
}

__global__ void scan1_k(const int* __restrict__ deg, int Nn, int* __restrict__ rp, int* __restrict__ bsum){
    __shared__ int s[256];
    int t = threadIdx.x, b = blockIdx.x;
    int i = b*256 + t;
    int v = (i < Nn) ? deg[i] : 0;
    s[t] = v;
    __syncthreads();
    #pragma unroll
    for (int d = 1; d < 256; d <<= 1){
        int u = (t >= d) ? s[t-d] : 0;
        __syncthreads();
        s[t] += u;
        __syncthreads();
    }
    if (i < Nn) rp[i] = s[t] - v;
    if (t == 255) bsum[b] = s[255];
}

__global__ void scan2_k(const int* __restrict__ bsum, int nb, int* __restrict__ bsumx){
    __shared__ int s[256];
    int t = threadIdx.x;
    int v = (t < nb) ? bsum[t] : 0;
    s[t] = v;
    __syncthreads();
    #pragma unroll
    for (int d = 1; d < 256; d <<= 1){
        int u = (t >= d) ? s[t-d] : 0;
        __syncthreads();
        s[t] += u;
        __syncthreads();
    }
    if (t < nb) bsumx[t] = s[t] - v;
}

__global__ void scan3_k(int* __restrict__ rp, const int* __restrict__ bsumx,
                        int* __restrict__ cnt, int Nn, int E){
    int b = blockIdx.x, t = threadIdx.x;
    int i = b*256 + t;
    if (i < Nn){
        int r = rp[i] + bsumx[b];
        rp[i]  = r;
        cnt[i] = r;
    }
    if (b == 0 && t == 0) rp[Nn] = E;
}

// items[rp[i]+i] = i  (self-loop slot)
__global__ void self_k(const int* __restrict__ rp, int* __restrict__ items, int Nn){
    int i = blockIdx.x*256 + threadIdx.x;
    if (i < Nn) items[rp[i] + i] = i;
}

// edges into items at CSR slot + dst + 1
__global__ void scatter_k(const int* __restrict__ src, const int* __restrict__ dst,
                          int E, int* __restrict__ cnt, int* __restrict__ items){
    int e = blockIdx.x*256 + threadIdx.x;
    if (e < E){
        int d = dst[e];
        int pos = atomicAdd(&cnt[d], 1);
        items[pos + d + 1] = src[e];
    }
}

// ---------------- conversions ----------------

__global__ void cvt_x_k(const float* __restrict__ X, _Float16* __restrict__ O, int n4){
    int i = blockIdx.x*256 + threadIdx.x;
    if (i >= n4) return;
    float4 v = reinterpret_cast<const float4*>(X)[i];
    U2 o;
    o.h[0][0] = (_Float16)v.x; o.h[0][1] = (_Float16)v.y;
    o.h[1][0] = (_Float16)v.z; o.h[1][1] = (_Float16)v.w;
    reinterpret_cast<uint2*>(O)[i] = o.u;
}

// weights [K][Nw] (two of them) -> transposed Bt[2*Nw][K] fp16
__global__ void cvt_w_k(const float* __restrict__ Wl, const float* __restrict__ Wr,
                        int Nw, int K, _Float16* __restrict__ Bt){
    int t = blockIdx.x*256 + threadIdx.x;
    int total = 2*Nw*K;
    if (t >= total) return;
    int k = t & (K-1);
    int n = t >> 8;                 // K == 256
    float v = (n < Nw) ? Wl[(size_t)k*Nw + n] : Wr[(size_t)k*Nw + (n - Nw)];
    Bt[t] = (_Float16)v;
}

__global__ void cvt_att_k(const float* __restrict__ a1, const float* __restrict__ a2,
                          _Float16* __restrict__ o1, _Float16* __restrict__ o2){
    int t = threadIdx.x;
    o1[t] = (_Float16)a1[t];
    if (t < 64) o2[t] = (_Float16)a2[t];
}

// ---------------- fp16 MFMA GEMM: C = A @ B, B given as Bt[Ntot][K], all fp16 ----------------
// Tile 128x128, 4 waves (2x2), 16x16x32 f16.
__global__ __launch_bounds__(256) void gemm_f16(
    const _Float16* __restrict__ A, const _Float16* __restrict__ Bt,
    _Float16* __restrict__ C, int M, int Ntot, int K)
{
    __shared__ __align__(16) _Float16 sA[128*40];
    __shared__ __align__(16) _Float16 sB[128*40];

    int t = threadIdx.x;
    int lane = t & 63, wave = t >> 6;
    int wm = (wave >> 1) * 64, wn = (wave & 1) * 64;
    int m0 = blockIdx.y * 128, n0 = blockIdx.x * 128;
    int lm = lane & 15, kq = lane >> 4;

    f32x4 acc[4][4] = {};

    for (int kc = 0; kc < K; kc += 32){
        __syncthreads();
        #pragma unroll
        for (int it = 0; it < 2; ++it){
            int idx = t + 256*it;
            int r = idx >> 2, s = (idx & 3) * 8;
            uint4 va = make_uint4(0u,0u,0u,0u);
            if (m0 + r < M)
                va = *reinterpret_cast<const uint4*>(A + (size_t)(m0 + r)*K + kc + s);
            *reinterpret_cast<uint4*>(sA + r*40 + s) = va;
            *reinterpret_cast<uint4*>(sB + r*40 + s) =
                *reinterpret_cast<const uint4*>(Bt + (size_t)(n0 + r)*K + kc + s);
        }
        __syncthreads();

        f16x8 fa[4], fb[4];
        #pragma unroll
        for (int i = 0; i < 4; ++i){
            fa[i] = *reinterpret_cast<const f16x8*>(sA + (wm + i*16 + lm)*40 + kq*8);
            fb[i] = *reinterpret_cast<const f16x8*>(sB + (wn + i*16 + lm)*40 + kq*8);
        }
        #pragma unroll
        for (int i = 0; i < 4; ++i)
            #pragma unroll
            for (int j = 0; j < 4; ++j)
                acc[i][j] = __builtin_amdgcn_mfma_f32_16x16x32_f16(fa[i], fb[j], acc[i][j], 0, 0, 0);
    }

    #pragma unroll
    for (int i = 0; i < 4; ++i){
        #pragma unroll
        for (int r = 0; r < 4; ++r){
            int m = m0 + wm + i*16 + kq*4 + r;
            if (m < M){
                #pragma unroll
                for (int j = 0; j < 4; ++j)
                    C[(size_t)m*Ntot + n0 + wn + j*16 + lm] = (_Float16)acc[i][j][r];
            }
        }
    }
}

// ---------------- layer-1 aggregation: wave per node, 2-edge ILP + 4-deep prefetch ----------------
// xlr [N][512] fp16: cols 0..255 = xl, 256..511 = xr. items = self+edges CSR.
__global__ __launch_bounds__(256) void agg1_k(
    const _Float16* __restrict__ xlr,
    const int* __restrict__ rp, const int* __restrict__ items,
    const _Float16* __restrict__ attH, const float* __restrict__ bias,
    _Float16* __restrict__ h1, int Nn)
{
    int wave = threadIdx.x >> 6, lane = threadIdx.x & 63;
    int i = blockIdx.x*4 + wave;
    if (i >= Nn) return;
    int off = lane*4;
    U2 xr; xr.u = *reinterpret_cast<const uint2*>(xlr + (size_t)i*512 + 256 + off);
    U2 at; at.u = *reinterpret_cast<const uint2*>(attH + off);
    int beg = rp[i] + i;
    int n   = rp[i+1] + 1 - rp[i];        // items count (>=1)

    auto rowld = [&](int j)->uint2 {
        int jj = (j < n) ? j : (n-1);
        int sn = items[beg + jj];
        return *reinterpret_cast<const uint2*>(xlr + (size_t)sn*512 + off);
    };

    float l = 0.f;
    float4 acc = make_float4(0.f,0.f,0.f,0.f);

    uint2 r0 = rowld(0), r1 = rowld(1), r2 = rowld(2), r3 = rowld(3);
    for (int j = 0; j < n; j += 2){
        uint2 p0 = rowld(j+4), p1 = rowld(j+5);
        U2 c0; c0.u = r0;
        U2 c1; c1.u = r1;
        float s0 = dot4_lrelu(c0.h[0], c0.h[1], xr.h[0], xr.h[1], at.h[0], at.h[1]);
        float s1 = dot4_lrelu(c1.h[0], c1.h[1], xr.h[0], xr.h[1], at.h[0], at.h[1]);
        s0 += __shfl_xor(s0, 8, 64);  s1 += __shfl_xor(s1, 8, 64);
        s0 += __shfl_xor(s0, 4, 64);  s1 += __shfl_xor(s1, 4, 64);
        s0 += __shfl_xor(s0, 2, 64);  s1 += __shfl_xor(s1, 2, 64);
        s0 += __shfl_xor(s0, 1, 64);  s1 += __shfl_xor(s1, 1, 64);
        float w0 = __expf(s0);
        float w1 = (j+1 < n) ? __expf(s1) : 0.f;
        l += w0 + w1;
        acc.x += w0*(float)c0.h[0][0] + w1*(float)c1.h[0][0];
        acc.y += w0*(float)c0.h[0][1] + w1*(float)c1.h[0][1];
        acc.z += w0*(float)c0.h[1][0] + w1*(float)c1.h[1][0];
        acc.w += w0*(float)c0.h[1][1] + w1*(float)c1.h[1][1];
        r0 = r2; r1 = r3; r2 = p0; r3 = p1;
    }

    float inv = 1.f / l;
    float4 b4 = *reinterpret_cast<const float4*>(&bias[off]);
    U2 o;
    o.h[0][0] = (_Float16)fmaxf(acc.x*inv + b4.x, 0.f);
    o.h[0][1] = (_Float16)fmaxf(acc.y*inv + b4.y, 0.f);
    o.h[1][0] = (_Float16)fmaxf(acc.z*inv + b4.z, 0.f);
    o.h[1][1] = (_Float16)fmaxf(acc.w*inv + b4.w, 0.f);
    *reinterpret_cast<uint2*>(h1 + (size_t)i*256 + off) = o.u;
}

// ---------------- layer-2 aggregation + final linear: wave per node, 4 quarters ----------------
// xlr [N][128] fp16: cols 0..63 = xl, 64..127 = xr.
__global__ __launch_bounds__(256) void agg2_k(
    const _Float16* __restrict__ xlr,
    const int* __restrict__ rp, const int* __restrict__ items,
    const _Float16* __restrict__ attH, const float* __restrict__ bias,
    const float* __restrict__ Wlin, const float* __restrict__ blin,
    float* __restrict__ out, int Nn)
{
    int wave = threadIdx.x >> 6, lane = threadIdx.x & 63;
    int i = blockIdx.x*4 + wave;
    if (i >= Nn) return;
    int q = lane >> 4, r = lane & 15;
    int off = r*4;
    U2 xr; xr.u = *reinterpret_cast<const uint2*>(xlr + (size_t)i*128 + 64 + off);
    U2 at; at.u = *reinterpret_cast<const uint2*>(attH + off);
    int beg = rp[i] + i;
    int n   = rp[i+1] + 1 - rp[i];

    auto rowld = [&](int j)->uint2 {
        int jj = (j < n) ? j : (n-1);
        int sn = items[beg + jj];
        return *reinterpret_cast<const uint2*>(xlr + (size_t)sn*128 + off);
    };

    float l = 0.f;
    float4 acc = make_float4(0.f,0.f,0.f,0.f);
    uint2 raw = rowld(q);
    for (int j = q; j < n; j += 4){
        uint2 nxt = rowld(j+4);
        U2 cv; cv.u = raw;
        float sc = dot4_lrelu(cv.h[0], cv.h[1], xr.h[0], xr.h[1], at.h[0], at.h[1]);
        sc += __shfl_xor(sc, 8, 64);
        sc += __shfl_xor(sc, 4, 64);
        sc += __shfl_xor(sc, 2, 64);
        sc += __shfl_xor(sc, 1, 64);
        float w = __expf(sc);
        l += w;
        acc.x = fmaf(w, (float)cv.h[0][0], acc.x);
        acc.y = fmaf(w, (float)cv.h[0][1], acc.y);
        acc.z = fmaf(w, (float)cv.h[1][0], acc.z);
        acc.w = fmaf(w, (float)cv.h[1][1], acc.w);
        raw = nxt;
    }
    #pragma unroll
    for (int s = 16; s <= 32; s <<= 1){
        l     += __shfl_xor(l, s, 64);
        acc.x += __shfl_xor(acc.x, s, 64);
        acc.y += __shfl_xor(acc.y, s, 64);
        acc.z += __shfl_xor(acc.z, s, 64);
        acc.w += __shfl_xor(acc.w, s, 64);
    }
    float inv = 1.f / l;
    float4 b4 = *reinterpret_cast<const float4*>(&bias[off]);
    float4 hc;
    hc.x = fmaxf(acc.x*inv + b4.x, 0.f);
    hc.y = fmaxf(acc.y*inv + b4.y, 0.f);
    hc.z = fmaxf(acc.z*inv + b4.z, 0.f);
    hc.w = fmaxf(acc.w*inv + b4.w, 0.f);
    for (int c = q; c < 10; c += 4){
        float p = hc.x * Wlin[(off+0)*10 + c]
                + hc.y * Wlin[(off+1)*10 + c]
                + hc.z * Wlin[(off+2)*10 + c]
                + hc.w * Wlin[(off+3)*10 + c];
        p += __shfl_xor(p, 8, 64);
        p += __shfl_xor(p, 4, 64);
        p += __shfl_xor(p, 2, 64);
        p += __shfl_xor(p, 1, 64);
        if (r == 0) out[(size_t)i*10 + c] = p + blin[c];
    }
}

// ---------------- launch ----------------

extern "C" void kernel_launch(void* const* d_in, const int* in_sizes, int n_in,
                              void* d_out, int out_size, void* d_ws, size_t ws_size,
                              hipStream_t stream)
{
    const float* x    = (const float*)d_in[0];
    const int*   ei   = (const int*)  d_in[1];
    const float* Wl1  = (const float*)d_in[2];
    const float* Wr1  = (const float*)d_in[3];
    const float* att1 = (const float*)d_in[4];
    const float* b1   = (const float*)d_in[5];
    const float* Wl2  = (const float*)d_in[6];
    const float* Wr2  = (const float*)d_in[7];
    const float* att2 = (const float*)d_in[8];
    const float* b2   = (const float*)d_in[9];
    const float* Wlin = (const float*)d_in[10];
    const float* blin = (const float*)d_in[11];
    float* out = (float*)d_out;

    const int N = in_sizes[0] / 256;
    const int E = in_sizes[1] / 2;
    const int K = 256;
    const int* srcp = ei;
    const int* dstp = ei + E;

    char* ws = (char*)d_ws;
    size_t off = 0;
    auto alloc = [&](size_t bytes)->char*{
        char* p = ws + off;
        off += (bytes + 255) & ~(size_t)255;
        return p;
    };
    _Float16* xlr1 = (_Float16*)alloc((size_t)N*512*2);   // layer-1 xl|xr fp16
    _Float16* xlr2 = (_Float16*)alloc((size_t)N*128*2);   // layer-2 xl|xr fp16
    _Float16* xA   = (_Float16*)alloc((size_t)N*256*2);   // x fp16
    _Float16* h1   = (_Float16*)alloc((size_t)N*256*2);   // h1 fp16
    _Float16* bt1  = (_Float16*)alloc((size_t)512*K*2);
    _Float16* bt2  = (_Float16*)alloc((size_t)128*K*2);
    _Float16* a1h  = (_Float16*)alloc(256*2);
    _Float16* a2h  = (_Float16*)alloc(64*2);
    int* rp    = (int*)alloc((size_t)(N+1)*4);
    int* cnt   = (int*)alloc((size_t)N*4);
    int* bsum  = (int*)alloc(256*4);
    int* bsumx = (int*)alloc(256*4);
    int* items = (int*)alloc((size_t)(E+N)*4);
    (void)ws_size;

    const int nb = (N + 255) / 256;
    const int eb = (E + 255) / 256;

    // CSR build (items = self + edges per node)
    hipLaunchKernelGGL(zero_int,  dim3(nb), dim3(256), 0, stream, cnt, N);
    hipLaunchKernelGGL(hist_k,    dim3(eb), dim3(256), 0, stream, dstp, E, cnt);
    hipLaunchKernelGGL(scan1_k,   dim3(nb), dim3(256), 0, stream, cnt, N, rp, bsum);
    hipLaunchKernelGGL(scan2_k,   dim3(1),  dim3(256), 0, stream, bsum, nb, bsumx);
    hipLaunchKernelGGL(scan3_k,   dim3(nb), dim3(256), 0, stream, rp, bsumx, cnt, N, E);
    hipLaunchKernelGGL(self_k,    dim3(nb), dim3(256), 0, stream, rp, items, N);
    hipLaunchKernelGGL(scatter_k, dim3(eb), dim3(256), 0, stream, srcp, dstp, E, cnt, items);

    // conversions
    hipLaunchKernelGGL(cvt_x_k, dim3((N*256/4 + 255)/256), dim3(256), 0, stream,
                       x, xA, N*256/4);
    hipLaunchKernelGGL(cvt_w_k, dim3((512*K + 255)/256), dim3(256), 0, stream,
                       Wl1, Wr1, 256, K, bt1);
    hipLaunchKernelGGL(cvt_w_k, dim3((128*K + 255)/256), dim3(256), 0, stream,
                       Wl2, Wr2, 64, K, bt2);
    hipLaunchKernelGGL(cvt_att_k, dim3(1), dim3(256), 0, stream, att1, att2, a1h, a2h);

    // layer 1
    hipLaunchKernelGGL(gemm_f16, dim3(4, (N+127)/128), dim3(256), 0, stream,
                       xA, bt1, xlr1, N, 512, K);
    hipLaunchKernelGGL(agg1_k, dim3((N+3)/4), dim3(256), 0, stream,
                       xlr1, rp, items, a1h, b1, h1, N);

    // layer 2
    hipLaunchKernelGGL(gemm_f16, dim3(1, (N+127)/128), dim3(256), 0, stream,
                       h1, bt2, xlr2, N, 128, K);
    hipLaunchKernelGGL(agg2_k, dim3((N+3)/4), dim3(256), 0, stream,
                       xlr2, rp, items, a2h, b2, Wlin, blin, out, N);
}